// Round 15
// baseline (217.650 us; speedup 1.0000x reference)
//
#include <hip/hip_runtime.h>
#include <hip/hip_bf16.h>

typedef __hip_bfloat16 bf16;
typedef __attribute__((ext_vector_type(8))) short bf16x8;
typedef __attribute__((ext_vector_type(4))) float f32x4;

constexpr int NB    = 64;
constexpr int EE    = 512;
constexpr int RPOS  = 27 * 27;       // 729
constexpr int ROWS  = NB * 14 * 14;  // 12544

#define RMS_EPS 1e-6f
#define GAMMA_LOG2 (-0.00144344319f)   // log2(0.999)

__device__ __forceinline__ void  stf(float* p, float v) { *p = v; }
__device__ __forceinline__ void  stf(bf16* p, float v)  { *p = __float2bfloat16(v); }

__device__ __forceinline__ void gload_lds16(const bf16* g, bf16* l) {
    __builtin_amdgcn_global_load_lds(
        (const __attribute__((address_space(1))) void*)g,
        (__attribute__((address_space(3))) void*)l, 16, 0, 0);
}

#define VMCNT(n) asm volatile("s_waitcnt vmcnt(" #n ")" ::: "memory")

// ---------------------------------------------------------------------------
// One-shot prep: 7 weight transposes (fp32 [R][C] -> bf16 [C][R]), bias
// concat, x -> bf16, RPE pos+norm, Vt pad-zero.
__global__ __launch_bounds__(256) void k_prep(const float* __restrict__ Wu,
                                              const float* __restrict__ Wv,
                                              const float* __restrict__ Wo,
                                              const float* __restrict__ w1,
                                              const float* __restrict__ w2,
                                              const float* __restrict__ w3,
                                              const float* __restrict__ wOut,
                                              const float* __restrict__ bu,
                                              const float* __restrict__ bv,
                                              const float* __restrict__ x,
                                              const float* __restrict__ rpw,
                                              const float* __restrict__ rpb,
                                              bf16* __restrict__ WuvT,
                                              bf16* __restrict__ WoT,
                                              bf16* __restrict__ w1T,
                                              bf16* __restrict__ w2T,
                                              bf16* __restrict__ w3T,
                                              bf16* __restrict__ wOutT,
                                              float* __restrict__ biasUv,
                                              bf16* __restrict__ xb,
                                              bf16* __restrict__ rnA,
                                              bf16* __restrict__ Vt) {
    __shared__ float t[32][33];
    __shared__ float ps[4];
    const int tid = threadIdx.x;
    int b = blockIdx.x;

    const float* src = nullptr; bf16* dst = nullptr; int R = 0, C = 0, nbx = 0;
    if (b < 512)        { src = Wu;   dst = WuvT;                      R = 512;  C = 1024; nbx = 32; }
    else if (b < 1024)  { b -= 512;   src = Wv; dst = WuvT + (size_t)1024 * 512; R = 512; C = 1024; nbx = 32; }
    else if (b < 1536)  { b -= 1024;  src = Wo;   dst = WoT;           R = 1024; C = 512;  nbx = 16; }
    else if (b < 1792)  { b -= 1536;  src = w1;   dst = w1T;           R = 512;  C = 512;  nbx = 16; }
    else if (b < 2048)  { b -= 1792;  src = w2;   dst = w2T;           R = 512;  C = 512;  nbx = 16; }
    else if (b < 2304)  { b -= 2048;  src = w3;   dst = w3T;           R = 512;  C = 512;  nbx = 16; }
    else if (b < 2816)  { b -= 2304;  src = wOut; dst = wOutT;         R = 512;  C = 1024; nbx = 32; }
    else if (b < 2824) {               // bias concat
        int c = (b - 2816) * 256 + tid;
        if (c < 2048) biasUv[c] = (c < 1024) ? bu[c] : bv[c - 1024];
        return;
    } else if (b < 9096) {             // x -> bf16
        int i = (b - 2824) * 256 + tid;
        float4 v = *(const float4*)&x[(size_t)i * 4];
        bf16* d = &xb[(size_t)i * 4];
        d[0] = __float2bfloat16(v.x);
        d[1] = __float2bfloat16(v.y);
        d[2] = __float2bfloat16(v.z);
        d[3] = __float2bfloat16(v.w);
        return;
    } else if (b < 9825) {             // RPE pos + rmsnorm + relu: 729 blocks
        int p = b - 9096;
        float ii = (float)(p / 27 - 13);
        float jj = (float)(p % 27 - 13);
        int c0 = tid, c1 = tid + 256;
        float v0 = ii * rpw[c0] + jj * rpw[512 + c0] + rpb[c0];
        float v1 = ii * rpw[c1] + jj * rpw[512 + c1] + rpb[c1];
        float s = v0 * v0 + v1 * v1;
        #pragma unroll
        for (int off = 32; off; off >>= 1) s += __shfl_down(s, off, 64);
        if ((tid & 63) == 0) ps[tid >> 6] = s;
        __syncthreads();
        float tot = ps[0] + ps[1] + ps[2] + ps[3];
        float scale = rsqrtf(tot * (1.0f / 512.0f) + RMS_EPS);
        rnA[(size_t)p * 512 + c0] = __float2bfloat16(fmaxf(v0 * scale, 0.0f));
        rnA[(size_t)p * 512 + c1] = __float2bfloat16(fmaxf(v1 * scale, 0.0f));
        return;
    } else {                           // Vt pad-zero: 1024 blocks, ij 196..223
        int c = b - 9825;
        const bf16 z = __float2bfloat16(0.0f);
        for (int f = tid; f < 64 * 28; f += 256) {
            int bb2 = f / 28, k = f - bb2 * 28;
            Vt[((size_t)c * 64 + bb2) * 224 + 196 + k] = z;
        }
        return;
    }
    int bx = (b % nbx) * 32;
    int by = (b / nbx) * 32;
    int tx = tid & 31, ty = tid >> 5;
    #pragma unroll
    for (int i = 0; i < 4; ++i)
        t[ty + i * 8][tx] = src[(size_t)(by + ty + i * 8) * C + bx + tx];
    __syncthreads();
    #pragma unroll
    for (int i = 0; i < 4; ++i)
        dst[(size_t)(bx + ty + i * 8) * R + by + tx] = __float2bfloat16(t[tx][ty + i * 8]);
}

// ---------------------------------------------------------------------------
// RPE-layer GEMM with fused norm bookkeeping (64x64 tile, BK=32, 4 waves).
// Identity: relu(rmsnorm(x)) @ W = s_row * (relu(x) @ W), s_row > 0.
template <int SCALE_IN, int EPI>
__global__ __launch_bounds__(256) void k_rpe_gemm(const bf16* __restrict__ A,
                                                  const bf16* __restrict__ Bt,
                                                  const float* __restrict__ bias,
                                                  const float* __restrict__ pIn,
                                                  float* __restrict__ pOut,
                                                  bf16* __restrict__ out,
                                                  int M, int N, int K) {
    __shared__ bf16 As[64 * 32];
    __shared__ bf16 Bs[64 * 32];
    const int tid = threadIdx.x;
    const int m0 = blockIdx.y * 64;
    const int n0 = blockIdx.x * 64;
    const int lane = tid & 63;
    const int w = tid >> 6;
    const int lr = lane & 15;
    const int lk = (lane >> 4) * 8;

    f32x4 acc[4] = {};
    const int row = tid >> 2;
    const int seg = (tid & 3) * 8;

    for (int k0 = 0; k0 < K; k0 += 32) {
        gload_lds16(&A[(size_t)(m0 + row) * K + k0 + seg], &As[tid * 8]);
        gload_lds16(&Bt[(size_t)(n0 + row) * K + k0 + seg], &Bs[tid * 8]);
        __syncthreads();
        bf16x8 af = *(const bf16x8*)&As[(w * 16 + lr) * 32 + lk];
        #pragma unroll
        for (int j = 0; j < 4; ++j) {
            bf16x8 bf = *(const bf16x8*)&Bs[(j * 16 + lr) * 32 + lk];
            acc[j] = __builtin_amdgcn_mfma_f32_16x16x32_bf16(af, bf, acc[j], 0, 0, 0);
        }
        __syncthreads();
    }

    const int crow = (lane >> 4) * 4;
    const int ccol = lane & 15;
    float sc[4];
    #pragma unroll
    for (int r = 0; r < 4; ++r) {
        sc[r] = 1.0f;
        if (SCALE_IN) {
            int gr = m0 + w * 16 + crow + r;
            if (gr < M) {
                const float* pp = &pIn[(size_t)gr * 8];
                float s8 = pp[0] + pp[1] + pp[2] + pp[3] + pp[4] + pp[5] + pp[6] + pp[7];
                sc[r] = rsqrtf(s8 * (1.0f / 512.0f) + RMS_EPS);
            }
        }
    }
    float rowsq[4] = {0.f, 0.f, 0.f, 0.f};
    #pragma unroll
    for (int j = 0; j < 4; ++j) {
        int gc = n0 + j * 16 + ccol;
        float bb = bias[gc];
        #pragma unroll
        for (int r = 0; r < 4; ++r) {
            int gr = m0 + w * 16 + crow + r;
            float val = acc[j][r] * sc[r] + bb;
            if (EPI == 0) {
                rowsq[r] += val * val;
                if (gr < M) out[(size_t)gr * N + gc] = __float2bfloat16(fmaxf(val, 0.0f));
            } else {
                if (gr < M) {
                    int i = gr / 27, jj = gr % 27;
                    float decay = exp2f((float)(abs(i - 13) + abs(jj - 13)) * GAMMA_LOG2);
                    out[(size_t)gr * N + gc] = __float2bfloat16(val * decay);
                }
            }
        }
    }
    if (EPI == 0) {
        #pragma unroll
        for (int r = 0; r < 4; ++r) {
            #pragma unroll
            for (int m = 1; m < 16; m <<= 1) rowsq[r] += __shfl_xor(rowsq[r], m, 64);
        }
        if ((lane & 15) == 0) {
            #pragma unroll
            for (int r = 0; r < 4; ++r) {
                int gr = m0 + w * 16 + crow + r;
                if (gr < M) pOut[(size_t)gr * 8 + blockIdx.x] = rowsq[r];
            }
        }
    }
}

// ---------------------------------------------------------------------------
// m97-structure 128x128 MFMA GEMM (out GEMM; ~3 blocks/CU).
template <int EPI, typename TO>
__global__ __launch_bounds__(256) void k_mgemm(const bf16* __restrict__ A, int lda,
                                               const bf16* __restrict__ Bt,
                                               const float* __restrict__ bias,
                                               TO* __restrict__ out, int ldo,
                                               int M, int N, int K) {
    __shared__ bf16 As[128 * 32];
    __shared__ bf16 Bs[128 * 32];
    const int tid = threadIdx.x;
    const int m0 = blockIdx.y * 128;
    const int n0 = blockIdx.x * 128;
    const int lane = tid & 63;
    const int w = tid >> 6;
    const int wr = (w >> 1) * 64;
    const int wc = (w & 1) * 64;
    const int lr = lane & 15;
    const int lk = (lane >> 4) * 8;

    f32x4 acc[4][4] = {};

    for (int k0 = 0; k0 < K; k0 += 32) {
        #pragma unroll
        for (int t = 0; t < 2; ++t) {
            int flat = t * 256 + tid;
            int row = flat >> 2;
            int seg = (flat & 3) * 8;
            gload_lds16(&A[(size_t)(m0 + row) * lda + k0 + seg], &As[flat * 8]);
            gload_lds16(&Bt[(size_t)(n0 + row) * K + k0 + seg], &Bs[flat * 8]);
        }
        __syncthreads();
        bf16x8 af[4], bf[4];
        #pragma unroll
        for (int i = 0; i < 4; ++i) {
            af[i] = *(const bf16x8*)&As[(wr + i * 16 + lr) * 32 + lk];
            bf[i] = *(const bf16x8*)&Bs[(wc + i * 16 + lr) * 32 + lk];
        }
        #pragma unroll
        for (int i = 0; i < 4; ++i)
            #pragma unroll
            for (int j = 0; j < 4; ++j)
                acc[i][j] = __builtin_amdgcn_mfma_f32_16x16x32_bf16(af[i], bf[j], acc[i][j], 0, 0, 0);
        __syncthreads();
    }

    const int crow = (lane >> 4) * 4;
    const int ccol = lane & 15;
    #pragma unroll
    for (int i = 0; i < 4; ++i)
        #pragma unroll
        for (int j = 0; j < 4; ++j) {
            int gc = n0 + wc + j * 16 + ccol;
            float bb = bias[gc];
            #pragma unroll
            for (int r = 0; r < 4; ++r) {
                int gr = m0 + wr + i * 16 + crow + r;
                float val = acc[i][j][r] + bb;
                if (EPI == 1) val = val / (1.0f + expf(-val));
                stf(&out[(size_t)gr * ldo + gc], val);
            }
        }
}

// ---------------------------------------------------------------------------
// 8-phase 256x256 MFMA GEMM (K-loop schedule frozen since R8; uv GEMM).
// EPI==1: u-half blocks (n0<1024) write silu to out row-major; v-half blocks
// (n0>=1024) transpose silu(acc) through the (dead) staging LDS and write
// channel-major Vt[c][b][ij pad 224] with contiguous 16B runs (replaces k_vt).
template <int KT, int EPI, typename TO>
__global__ __launch_bounds__(512, 2) void k_mgemm8(const bf16* __restrict__ A, int lda,
                                                   const bf16* __restrict__ Bt,
                                                   const float* __restrict__ bias,
                                                   TO* __restrict__ out, int ldo,
                                                   int nb /* N/256 */,
                                                   bf16* __restrict__ Vt) {
    constexpr int K = KT * 64;
    __shared__ __align__(16) char lds[131072];

    const int tid = threadIdx.x;
    const int lane = tid & 63;
    const int wid = tid >> 6;
    const int wr = wid >> 2;
    const int wc = wid & 3;

    int wgid = blockIdx.x;
    if ((gridDim.x & 7) == 0) {
        int cpx = gridDim.x >> 3;
        wgid = (wgid & 7) * cpx + (wgid >> 3);
    }
    const int m0 = (wgid / nb) * 256;
    const int n0 = (wgid % nb) * 256;

    auto ldsA = [&](int d, int kh) -> char* { return (char*)lds + d * 32768 + kh * 16384; };
    auto ldsB = [&](int d, int kh) -> char* { return (char*)lds + 65536 + d * 32768 + kh * 16384; };

    auto stage = [&](int op, int kh, int tt) {
        char* base = op ? ldsB(tt & 1, kh) : ldsA(tt & 1, kh);
        const bf16* g = op ? Bt : A;
        const int rowbase = op ? n0 : m0;
        const int ldr = op ? K : lda;
        #pragma unroll
        for (int l = 0; l < 2; ++l) {
            int q = tid + l * 512;
            int r = q >> 2;
            int cl = (q & 3) ^ ((r ^ (r >> 2)) & 3);
            const bf16* src = g + (size_t)(rowbase + r) * ldr + tt * 64 + kh * 32 + cl * 8;
            gload_lds16(src, (bf16*)(base + q * 16));
        }
    };
    auto rdA = [&](int d, int ks, int mi) -> bf16x8 {
        int row = wr * 128 + mi * 16 + (lane & 15);
        int ch = (lane >> 4) ^ ((row ^ (row >> 2)) & 3);
        return *(const bf16x8*)(ldsA(d, ks) + row * 64 + ch * 16);
    };
    auto rdB = [&](int d, int ks, int nj) -> bf16x8 {
        int row = wc * 64 + nj * 16 + (lane & 15);
        int ch = (lane >> 4) ^ ((row ^ (row >> 2)) & 3);
        return *(const bf16x8*)(ldsB(d, ks) + row * 64 + ch * 16);
    };

    f32x4 acc[8][4] = {};
    bf16x8 aF[4], bF[4];

    stage(0, 0, 0); stage(1, 0, 0); stage(0, 1, 0); stage(1, 1, 0);
    stage(0, 0, 1); stage(1, 0, 1);
    VMCNT(8);
    __builtin_amdgcn_s_barrier();
    __builtin_amdgcn_sched_barrier(0);

    #pragma unroll
    for (int t = 0; t < KT; ++t) {
        const int d = t & 1;
        #pragma unroll
        for (int mi = 0; mi < 4; ++mi) aF[mi] = rdA(d, 0, mi);
        #pragma unroll
        for (int nj = 0; nj < 4; ++nj) bF[nj] = rdB(d, 0, nj);
        if (t + 1 < KT) stage(0, 1, t + 1);
        __builtin_amdgcn_s_barrier();
        __builtin_amdgcn_s_setprio(1);
        #pragma unroll
        for (int mi = 0; mi < 4; ++mi)
            #pragma unroll
            for (int nj = 0; nj < 4; ++nj)
                acc[mi][nj] = __builtin_amdgcn_mfma_f32_16x16x32_bf16(aF[mi], bF[nj], acc[mi][nj], 0, 0, 0);
        __builtin_amdgcn_s_setprio(0);
        __builtin_amdgcn_s_barrier();
        #pragma unroll
        for (int mi = 0; mi < 4; ++mi) aF[mi] = rdA(d, 0, mi + 4);
        if (t + 1 < KT) stage(1, 1, t + 1);
        if (t + 1 < KT) { VMCNT(8); } else { VMCNT(0); }
        __builtin_amdgcn_s_barrier();
        __builtin_amdgcn_sched_barrier(0);
        __builtin_amdgcn_s_setprio(1);
        #pragma unroll
        for (int mi = 0; mi < 4; ++mi)
            #pragma unroll
            for (int nj = 0; nj < 4; ++nj)
                acc[mi + 4][nj] = __builtin_amdgcn_mfma_f32_16x16x32_bf16(aF[mi], bF[nj], acc[mi + 4][nj], 0, 0, 0);
        __builtin_amdgcn_s_setprio(0);
        __builtin_amdgcn_s_barrier();
        #pragma unroll
        for (int mi = 0; mi < 4; ++mi) aF[mi] = rdA(d, 1, mi);
        #pragma unroll
        for (int nj = 0; nj < 4; ++nj) bF[nj] = rdB(d, 1, nj);
        if (t + 2 < KT) stage(0, 0, t + 2);
        __builtin_amdgcn_s_barrier();
        __builtin_amdgcn_s_setprio(1);
        #pragma unroll
        for (int mi = 0; mi < 4; ++mi)
            #pragma unroll
            for (int nj = 0; nj < 4; ++nj)
                acc[mi][nj] = __builtin_amdgcn_mfma_f32_16x16x32_bf16(aF[mi], bF[nj], acc[mi][nj], 0, 0, 0);
        __builtin_amdgcn_s_setprio(0);
        __builtin_amdgcn_s_barrier();
        #pragma unroll
        for (int mi = 0; mi < 4; ++mi) aF[mi] = rdA(d, 1, mi + 4);
        if (t + 2 < KT) stage(1, 0, t + 2);
        if (t + 2 < KT)      { VMCNT(8); }
        else if (t + 1 < KT) { VMCNT(4); }
        __builtin_amdgcn_s_barrier();
        __builtin_amdgcn_sched_barrier(0);
        __builtin_amdgcn_s_setprio(1);
        #pragma unroll
        for (int mi = 0; mi < 4; ++mi)
            #pragma unroll
            for (int nj = 0; nj < 4; ++nj)
                acc[mi + 4][nj] = __builtin_amdgcn_mfma_f32_16x16x32_bf16(aF[mi], bF[nj], acc[mi + 4][nj], 0, 0, 0);
        __builtin_amdgcn_s_setprio(0);
        __builtin_amdgcn_s_barrier();
    }

    const int crow = (lane >> 4) * 4;
    const int ccol = lane & 15;

    if (EPI == 1 && n0 >= 1024) {
        // v-half: silu -> LDS[col][row^sw] -> Vt[c][b][ij] contiguous runs
        bf16* ldsT = (bf16*)lds;
        __syncthreads();
        #pragma unroll
        for (int nj = 0; nj < 4; ++nj) {
            int lcol = wc * 64 + nj * 16 + ccol;
            float bb = bias[n0 + lcol];
            int sw = (lcol & 7) << 3;
            #pragma unroll
            for (int mi = 0; mi < 8; ++mi)
                #pragma unroll
                for (int r = 0; r < 4; ++r) {
                    int lrow = wr * 128 + mi * 16 + crow + r;
                    float val = acc[mi][nj][r] + bb;
                    val = val / (1.0f + expf(-val));
                    ldsT[lcol * 256 + (lrow ^ sw)] = __float2bfloat16(val);
                }
        }
        __syncthreads();
        const int colL = tid & 255;        // wave-uniform half: waves 0-3 / 4-7
        const int half = tid >> 8;
        const size_t cbase = (size_t)(n0 - 1024 + colL) * 64;
        const int swr = (colL & 7) << 3;
        #pragma unroll
        for (int ch = 0; ch < 16; ++ch) {
            int rb = half * 128 + ch * 8;
            bf16x8 v8 = *(const bf16x8*)&ldsT[colL * 256 + (rb ^ swr)];
            int grow = m0 + rb;
            int b0 = grow / 196;
            int ij0 = grow - b0 * 196;
            if (ij0 <= 188) {              // no b-boundary straddle
                unsigned int* d4 = (unsigned int*)&Vt[(cbase + b0) * 224 + ij0];
                const unsigned int* s4 = (const unsigned int*)&v8;
                d4[0] = s4[0]; d4[1] = s4[1]; d4[2] = s4[2]; d4[3] = s4[3];
            } else {
                #pragma unroll
                for (int j = 0; j < 8; ++j) {
                    int g = grow + j;
                    int b = g / 196, ij = g - b * 196;
                    Vt[(cbase + b) * 224 + ij] = ((const bf16*)&v8)[j];
                }
            }
        }
        return;
    }

    #pragma unroll
    for (int mi = 0; mi < 8; ++mi)
        #pragma unroll
        for (int nj = 0; nj < 4; ++nj) {
            int gc = n0 + wc * 64 + nj * 16 + ccol;
            float bb = bias[gc];
            #pragma unroll
            for (int r = 0; r < 4; ++r) {
                int gr = m0 + wr * 128 + mi * 16 + crow + r;
                float val = acc[mi][nj][r] + bb;
                if (EPI == 1) val = val / (1.0f + expf(-val));
                stf(&out[(size_t)gr * ldo + gc], val);
            }
        }
}

// ---------------------------------------------------------------------------
// Per-channel Toeplitz GEMM, both halves via blockIdx.z.
__global__ __launch_bounds__(256) void k_convm(const bf16* __restrict__ Ab,
                                               const bf16* __restrict__ Vt,
                                               bf16* __restrict__ Yt) {
    __shared__ __align__(16) bf16 Ts[112 * 232];
    __shared__ bf16 As[736];
    const int mh = blockIdx.x;
    const int cl = blockIdx.y;
    const int c = (int)blockIdx.z * 512 + cl;
    const int tid = threadIdx.x;
    const int mbase = mh * 112;

    for (int e = tid; e < 729; e += 256)
        As[e] = Ab[(size_t)e * 1024 + c];
    __syncthreads();

    const bf16 z = __float2bfloat16(0.0f);
    if (tid < 224) {
        const int i = tid / 14, j = tid - i * 14;
        const bool kvalid = tid < 196;
        int p = mbase / 14, q = 0;
        for (int r = 0; r < 112; ++r) {
            bf16 val = z;
            if (kvalid && (mbase + r) < 196)
                val = As[(p - i + 13) * 27 + (q - j + 13)];
            Ts[r * 232 + tid] = val;
            if (++q == 14) { q = 0; ++p; }
        }
    }
    __syncthreads();

    const int lane = tid & 63;
    const int w = tid >> 6;
    const int lr = lane & 15;
    const int lk = (lane >> 4) * 8;
    const bf16* Vc = Vt + (size_t)c * 64 * 224;

    bf16x8 bfr[7];
    #pragma unroll
    for (int ks = 0; ks < 7; ++ks)
        bfr[ks] = *(const bf16x8*)&Vc[(size_t)(w * 16 + lr) * 224 + ks * 32 + lk];

    f32x4 acc[7] = {};
    #pragma unroll
    for (int ks = 0; ks < 7; ++ks)
        #pragma unroll
        for (int mi = 0; mi < 7; ++mi) {
            bf16x8 a = *(const bf16x8*)&Ts[(mi * 16 + lr) * 232 + ks * 32 + lk];
            acc[mi] = __builtin_amdgcn_mfma_f32_16x16x32_bf16(a, bfr[ks], acc[mi], 0, 0, 0);
        }

    const int crow = (lane >> 4) * 4;
    const int bb = w * 16 + (lane & 15);
    #pragma unroll
    for (int mi = 0; mi < 7; ++mi) {
        int pq = mbase + mi * 16 + crow;
        #pragma unroll
        for (int r = 0; r < 4; ++r)
            if (pq + r < 196)
                Yt[((size_t)c * 196 + pq + r) * 64 + bb] = __float2bfloat16(acc[mi][r]);
    }
}

// ---------------------------------------------------------------------------
__global__ __launch_bounds__(256) void k_gate(bf16* __restrict__ uv,
                                              const bf16* __restrict__ Yt) {
    const int pq = blockIdx.x;
    const int ct = blockIdx.y;
    const int cb = (int)blockIdx.z * 512;
    const int tid = threadIdx.x;
    __shared__ float t[64][65];
    for (int f = tid; f < 64 * 64; f += 256) {
        int cr = f >> 6, bcol = f & 63;
        t[cr][bcol] = __bfloat162float(Yt[((size_t)(cb + ct * 64 + cr) * 196 + pq) * 64 + bcol]);
    }
    __syncthreads();
    for (int f = tid; f < 64 * 64; f += 256) {
        int br = f >> 6, cc = f & 63;
        size_t row = (size_t)br * 196 + pq;
        int cglob = cb + ct * 64 + cc;
        float uu = __bfloat162float(uv[row * 2048 + cglob]);
        uv[row * 2048 + 1024 + cglob] = __float2bfloat16(t[cc][br] * uu);
    }
}

// ---------------------------------------------------------------------------
extern "C" void kernel_launch(void* const* d_in, const int* in_sizes, int n_in,
                              void* d_out, int out_size, void* d_ws, size_t ws_size,
                              hipStream_t stream) {
    const float* x    = (const float*)d_in[0];
    const float* Wu   = (const float*)d_in[3];
    const float* bu   = (const float*)d_in[4];
    const float* Wv   = (const float*)d_in[5];
    const float* bv   = (const float*)d_in[6];
    const float* Wo   = (const float*)d_in[7];
    const float* bo   = (const float*)d_in[8];
    const float* rpw  = (const float*)d_in[9];
    const float* rpb  = (const float*)d_in[10];
    const float* w1   = (const float*)d_in[11];
    const float* b1   = (const float*)d_in[12];
    const float* w2   = (const float*)d_in[13];
    const float* b2   = (const float*)d_in[14];
    const float* w3   = (const float*)d_in[15];
    const float* b3   = (const float*)d_in[16];
    const float* wOut = (const float*)d_in[17];
    const float* bOut = (const float*)d_in[18];

    char* ws = (char*)d_ws;
    size_t off = 0;
    auto take = [&](size_t bytes) { char* p = ws + off; off += (bytes + 255) & ~size_t(255); return p; };
    bf16*  rnA    = (bf16*)take((size_t)768 * 512 * 2);
    bf16*  rnB    = (bf16*)take((size_t)768 * 512 * 2);
    float* p1     = (float*)take((size_t)768 * 8 * 4);
    float* p2     = (float*)take((size_t)768 * 8 * 4);
    float* p3     = (float*)take((size_t)768 * 8 * 4);
    bf16*  Ab     = (bf16*)take((size_t)RPOS * 1024 * 2);
    bf16*  xb     = (bf16*)take((size_t)ROWS * EE * 2);
    bf16*  WuvT   = (bf16*)take((size_t)2048 * 512 * 2);
    bf16*  WoT    = (bf16*)take((size_t)512 * 1024 * 2);
    bf16*  w1T    = (bf16*)take((size_t)512 * 512 * 2);
    bf16*  w2T    = (bf16*)take((size_t)512 * 512 * 2);
    bf16*  w3T    = (bf16*)take((size_t)512 * 512 * 2);
    bf16*  wOutT  = (bf16*)take((size_t)1024 * 512 * 2);
    float* biasUv = (float*)take(2048 * 4);
    bf16*  uvb    = (bf16*)take((size_t)ROWS * 2048 * 2);
    bf16*  Vt     = (bf16*)take((size_t)1024 * 64 * 224 * 2);
    bf16*  Yt     = (bf16*)take((size_t)1024 * 196 * 64 * 2);

    // --- all prep (weights, bias, x->bf16, RPE pos+norm, Vt pad) ---
    k_prep<<<10849, 256, 0, stream>>>(Wu, Wv, Wo, w1, w2, w3, wOut, bu, bv, x,
                                      rpw, rpb,
                                      WuvT, WoT, w1T, w2T, w3T, wOutT, biasUv, xb,
                                      rnA, Vt);

    // --- RPE MLP: 4 GEMMs with fused norm bookkeeping ---
    k_rpe_gemm<0, 0><<<dim3(8, 12), 256, 0, stream>>>(rnA, w1T, b1, nullptr, p1, rnB, RPOS, 512, 512);
    k_rpe_gemm<1, 0><<<dim3(8, 12), 256, 0, stream>>>(rnB, w2T, b2, p1, p2, rnA, RPOS, 512, 512);
    k_rpe_gemm<1, 0><<<dim3(8, 12), 256, 0, stream>>>(rnA, w3T, b3, p2, p3, rnB, RPOS, 512, 512);
    k_rpe_gemm<1, 2><<<dim3(16, 12), 256, 0, stream>>>(rnB, wOutT, bOut, p3, nullptr, Ab, RPOS, 1024, 512);

    // --- uv GEMM: u -> uvb rows, v -> Vt channel-major via LDS transpose ---
    k_mgemm8<8, 1, bf16><<<392, 512, 0, stream>>>(xb, 512, WuvT, biasUv, uvb, 2048, 8, Vt);

    // --- Toeplitz conv (MFMA) + gating ---
    k_convm<<<dim3(2, 512, 2), 256, 0, stream>>>(Ab, Vt, Yt);
    k_gate<<<dim3(196, 8, 2), 256, 0, stream>>>(uvb, Yt);

    // --- out = g @ Wo + bo  (m97 128^2, grid 392) ---
    k_mgemm<0, float><<<dim3(4, 98), 256, 0, stream>>>(uvb + 1024, 2048, WoT, bo,
                                                       (float*)d_out, 512, ROWS, 512, 1024);
}

// Round 16
// 214.655 us; speedup vs baseline: 1.0140x; 1.0140x over previous
//
#include <hip/hip_runtime.h>
#include <hip/hip_bf16.h>

typedef __hip_bfloat16 bf16;
typedef __attribute__((ext_vector_type(8))) short bf16x8;
typedef __attribute__((ext_vector_type(4))) float f32x4;

constexpr int NB    = 64;
constexpr int EE    = 512;
constexpr int RPOS  = 27 * 27;       // 729
constexpr int ROWS  = NB * 14 * 14;  // 12544

#define RMS_EPS 1e-6f
#define GAMMA_LOG2 (-0.00144344319f)   // log2(0.999)

__device__ __forceinline__ void  stf(float* p, float v) { *p = v; }
__device__ __forceinline__ void  stf(bf16* p, float v)  { *p = __float2bfloat16(v); }

__device__ __forceinline__ void gload_lds16(const bf16* g, bf16* l) {
    __builtin_amdgcn_global_load_lds(
        (const __attribute__((address_space(1))) void*)g,
        (__attribute__((address_space(3))) void*)l, 16, 0, 0);
}

#define VMCNT(n) asm volatile("s_waitcnt vmcnt(" #n ")" ::: "memory")

// ---------------------------------------------------------------------------
// One-shot prep: 7 weight transposes (fp32 [R][C] -> bf16 [C][R]), bias
// concat, x -> bf16, RPE pos+norm.
__global__ __launch_bounds__(256) void k_prep(const float* __restrict__ Wu,
                                              const float* __restrict__ Wv,
                                              const float* __restrict__ Wo,
                                              const float* __restrict__ w1,
                                              const float* __restrict__ w2,
                                              const float* __restrict__ w3,
                                              const float* __restrict__ wOut,
                                              const float* __restrict__ bu,
                                              const float* __restrict__ bv,
                                              const float* __restrict__ x,
                                              const float* __restrict__ rpw,
                                              const float* __restrict__ rpb,
                                              bf16* __restrict__ WuvT,
                                              bf16* __restrict__ WoT,
                                              bf16* __restrict__ w1T,
                                              bf16* __restrict__ w2T,
                                              bf16* __restrict__ w3T,
                                              bf16* __restrict__ wOutT,
                                              float* __restrict__ biasUv,
                                              bf16* __restrict__ xb,
                                              bf16* __restrict__ rnA) {
    __shared__ float t[32][33];
    __shared__ float ps[4];
    const int tid = threadIdx.x;
    int b = blockIdx.x;

    const float* src = nullptr; bf16* dst = nullptr; int R = 0, C = 0, nbx = 0;
    if (b < 512)        { src = Wu;   dst = WuvT;                      R = 512;  C = 1024; nbx = 32; }
    else if (b < 1024)  { b -= 512;   src = Wv; dst = WuvT + (size_t)1024 * 512; R = 512; C = 1024; nbx = 32; }
    else if (b < 1536)  { b -= 1024;  src = Wo;   dst = WoT;           R = 1024; C = 512;  nbx = 16; }
    else if (b < 1792)  { b -= 1536;  src = w1;   dst = w1T;           R = 512;  C = 512;  nbx = 16; }
    else if (b < 2048)  { b -= 1792;  src = w2;   dst = w2T;           R = 512;  C = 512;  nbx = 16; }
    else if (b < 2304)  { b -= 2048;  src = w3;   dst = w3T;           R = 512;  C = 512;  nbx = 16; }
    else if (b < 2816)  { b -= 2304;  src = wOut; dst = wOutT;         R = 512;  C = 1024; nbx = 32; }
    else if (b < 2824) {               // bias concat
        int c = (b - 2816) * 256 + tid;
        if (c < 2048) biasUv[c] = (c < 1024) ? bu[c] : bv[c - 1024];
        return;
    } else if (b < 9096) {             // x -> bf16
        int i = (b - 2824) * 256 + tid;
        float4 v = *(const float4*)&x[(size_t)i * 4];
        bf16* d = &xb[(size_t)i * 4];
        d[0] = __float2bfloat16(v.x);
        d[1] = __float2bfloat16(v.y);
        d[2] = __float2bfloat16(v.z);
        d[3] = __float2bfloat16(v.w);
        return;
    } else {                           // RPE pos + rmsnorm + relu: 729 blocks
        int p = b - 9096;
        float ii = (float)(p / 27 - 13);
        float jj = (float)(p % 27 - 13);
        int c0 = tid, c1 = tid + 256;
        float v0 = ii * rpw[c0] + jj * rpw[512 + c0] + rpb[c0];
        float v1 = ii * rpw[c1] + jj * rpw[512 + c1] + rpb[c1];
        float s = v0 * v0 + v1 * v1;
        #pragma unroll
        for (int off = 32; off; off >>= 1) s += __shfl_down(s, off, 64);
        if ((tid & 63) == 0) ps[tid >> 6] = s;
        __syncthreads();
        float tot = ps[0] + ps[1] + ps[2] + ps[3];
        float scale = rsqrtf(tot * (1.0f / 512.0f) + RMS_EPS);
        rnA[(size_t)p * 512 + c0] = __float2bfloat16(fmaxf(v0 * scale, 0.0f));
        rnA[(size_t)p * 512 + c1] = __float2bfloat16(fmaxf(v1 * scale, 0.0f));
        return;
    }
    int bx = (b % nbx) * 32;
    int by = (b / nbx) * 32;
    int tx = tid & 31, ty = tid >> 5;
    #pragma unroll
    for (int i = 0; i < 4; ++i)
        t[ty + i * 8][tx] = src[(size_t)(by + ty + i * 8) * C + bx + tx];
    __syncthreads();
    #pragma unroll
    for (int i = 0; i < 4; ++i)
        dst[(size_t)(bx + ty + i * 8) * R + by + tx] = __float2bfloat16(t[tx][ty + i * 8]);
}

// ---------------------------------------------------------------------------
// RPE-layer GEMM with fused norm bookkeeping (64x64 tile, BK=32, 4 waves).
// Double-buffered staging with counted vmcnt (these dispatches run <1
// block/CU, so there is no cross-block TLP to hide load latency; dbuf
// overlaps stage(t+1) with mfma(t)). Ordering pattern mirrors k_mgemm8
// (reads after the guaranteeing VMCNT+barrier), proven since R8.
// Identity: relu(rmsnorm(x)) @ W = s_row * (relu(x) @ W), s_row > 0.
template <int SCALE_IN, int EPI>
__global__ __launch_bounds__(256) void k_rpe_gemm(const bf16* __restrict__ A,
                                                  const bf16* __restrict__ Bt,
                                                  const float* __restrict__ bias,
                                                  const float* __restrict__ pIn,
                                                  float* __restrict__ pOut,
                                                  bf16* __restrict__ out,
                                                  int M, int N, int K) {
    __shared__ bf16 As[2][64 * 32];
    __shared__ bf16 Bs[2][64 * 32];
    const int tid = threadIdx.x;
    const int m0 = blockIdx.y * 64;
    const int n0 = blockIdx.x * 64;
    const int lane = tid & 63;
    const int w = tid >> 6;
    const int lr = lane & 15;
    const int lk = (lane >> 4) * 8;
    const int row = tid >> 2;
    const int seg = (tid & 3) * 8;

    auto stage = [&](int t, int d) {
        gload_lds16(&A[(size_t)(m0 + row) * K + t * 32 + seg], &As[d][tid * 8]);
        gload_lds16(&Bt[(size_t)(n0 + row) * K + t * 32 + seg], &Bs[d][tid * 8]);
    };

    f32x4 acc[4] = {};
    const int KT = K >> 5;             // K/32 steps

    stage(0, 0);                       // 2 loads in flight
    for (int t = 0; t < KT; ++t) {
        const int d = t & 1;
        if (t + 1 < KT) {
            stage(t + 1, d ^ 1);       // +2 -> 4 in flight
            VMCNT(2);                  // step t's pair landed (per-thread)
        } else {
            VMCNT(0);
        }
        __builtin_amdgcn_s_barrier();  // all threads' step-t data in LDS
        __builtin_amdgcn_sched_barrier(0);
        bf16x8 af = *(const bf16x8*)&As[d][(w * 16 + lr) * 32 + lk];
        #pragma unroll
        for (int j = 0; j < 4; ++j) {
            bf16x8 bf = *(const bf16x8*)&Bs[d][(j * 16 + lr) * 32 + lk];
            acc[j] = __builtin_amdgcn_mfma_f32_16x16x32_bf16(af, bf, acc[j], 0, 0, 0);
        }
        __builtin_amdgcn_s_barrier();  // reads of buf d done before t+1 issues into it
    }

    const int crow = (lane >> 4) * 4;
    const int ccol = lane & 15;
    float sc[4];
    #pragma unroll
    for (int r = 0; r < 4; ++r) {
        sc[r] = 1.0f;
        if (SCALE_IN) {
            int gr = m0 + w * 16 + crow + r;
            if (gr < M) {
                const float* pp = &pIn[(size_t)gr * 8];
                float s8 = pp[0] + pp[1] + pp[2] + pp[3] + pp[4] + pp[5] + pp[6] + pp[7];
                sc[r] = rsqrtf(s8 * (1.0f / 512.0f) + RMS_EPS);
            }
        }
    }
    float rowsq[4] = {0.f, 0.f, 0.f, 0.f};
    #pragma unroll
    for (int j = 0; j < 4; ++j) {
        int gc = n0 + j * 16 + ccol;
        float bb = bias[gc];
        #pragma unroll
        for (int r = 0; r < 4; ++r) {
            int gr = m0 + w * 16 + crow + r;
            float val = acc[j][r] * sc[r] + bb;
            if (EPI == 0) {
                rowsq[r] += val * val;
                if (gr < M) out[(size_t)gr * N + gc] = __float2bfloat16(fmaxf(val, 0.0f));
            } else {
                if (gr < M) {
                    int i = gr / 27, jj = gr % 27;
                    float decay = exp2f((float)(abs(i - 13) + abs(jj - 13)) * GAMMA_LOG2);
                    out[(size_t)gr * N + gc] = __float2bfloat16(val * decay);
                }
            }
        }
    }
    if (EPI == 0) {
        #pragma unroll
        for (int r = 0; r < 4; ++r) {
            #pragma unroll
            for (int m = 1; m < 16; m <<= 1) rowsq[r] += __shfl_xor(rowsq[r], m, 64);
        }
        if ((lane & 15) == 0) {
            #pragma unroll
            for (int r = 0; r < 4; ++r) {
                int gr = m0 + w * 16 + crow + r;
                if (gr < M) pOut[(size_t)gr * 8 + blockIdx.x] = rowsq[r];
            }
        }
    }
}

// ---------------------------------------------------------------------------
// m97-structure 128x128 MFMA GEMM (out GEMM; ~3 blocks/CU).
template <int EPI, typename TO>
__global__ __launch_bounds__(256) void k_mgemm(const bf16* __restrict__ A, int lda,
                                               const bf16* __restrict__ Bt,
                                               const float* __restrict__ bias,
                                               TO* __restrict__ out, int ldo,
                                               int M, int N, int K) {
    __shared__ bf16 As[128 * 32];
    __shared__ bf16 Bs[128 * 32];
    const int tid = threadIdx.x;
    const int m0 = blockIdx.y * 128;
    const int n0 = blockIdx.x * 128;
    const int lane = tid & 63;
    const int w = tid >> 6;
    const int wr = (w >> 1) * 64;
    const int wc = (w & 1) * 64;
    const int lr = lane & 15;
    const int lk = (lane >> 4) * 8;

    f32x4 acc[4][4] = {};

    for (int k0 = 0; k0 < K; k0 += 32) {
        #pragma unroll
        for (int t = 0; t < 2; ++t) {
            int flat = t * 256 + tid;
            int row = flat >> 2;
            int seg = (flat & 3) * 8;
            gload_lds16(&A[(size_t)(m0 + row) * lda + k0 + seg], &As[flat * 8]);
            gload_lds16(&Bt[(size_t)(n0 + row) * K + k0 + seg], &Bs[flat * 8]);
        }
        __syncthreads();
        bf16x8 af[4], bf[4];
        #pragma unroll
        for (int i = 0; i < 4; ++i) {
            af[i] = *(const bf16x8*)&As[(wr + i * 16 + lr) * 32 + lk];
            bf[i] = *(const bf16x8*)&Bs[(wc + i * 16 + lr) * 32 + lk];
        }
        #pragma unroll
        for (int i = 0; i < 4; ++i)
            #pragma unroll
            for (int j = 0; j < 4; ++j)
                acc[i][j] = __builtin_amdgcn_mfma_f32_16x16x32_bf16(af[i], bf[j], acc[i][j], 0, 0, 0);
        __syncthreads();
    }

    const int crow = (lane >> 4) * 4;
    const int ccol = lane & 15;
    #pragma unroll
    for (int i = 0; i < 4; ++i)
        #pragma unroll
        for (int j = 0; j < 4; ++j) {
            int gc = n0 + wc + j * 16 + ccol;
            float bb = bias[gc];
            #pragma unroll
            for (int r = 0; r < 4; ++r) {
                int gr = m0 + wr + i * 16 + crow + r;
                float val = acc[i][j][r] + bb;
                if (EPI == 1) val = val / (1.0f + expf(-val));
                stf(&out[(size_t)gr * ldo + gc], val);
            }
        }
}

// ---------------------------------------------------------------------------
// 8-phase 256x256 MFMA GEMM (frozen since R8; uv GEMM).
template <int KT, int EPI, typename TO>
__global__ __launch_bounds__(512, 2) void k_mgemm8(const bf16* __restrict__ A, int lda,
                                                   const bf16* __restrict__ Bt,
                                                   const float* __restrict__ bias,
                                                   TO* __restrict__ out, int ldo,
                                                   int nb /* N/256 */) {
    constexpr int K = KT * 64;
    __shared__ __align__(16) char lds[131072];

    const int tid = threadIdx.x;
    const int lane = tid & 63;
    const int wid = tid >> 6;
    const int wr = wid >> 2;
    const int wc = wid & 3;

    int wgid = blockIdx.x;
    if ((gridDim.x & 7) == 0) {
        int cpx = gridDim.x >> 3;
        wgid = (wgid & 7) * cpx + (wgid >> 3);
    }
    const int m0 = (wgid / nb) * 256;
    const int n0 = (wgid % nb) * 256;

    auto ldsA = [&](int d, int kh) -> char* { return (char*)lds + d * 32768 + kh * 16384; };
    auto ldsB = [&](int d, int kh) -> char* { return (char*)lds + 65536 + d * 32768 + kh * 16384; };

    auto stage = [&](int op, int kh, int tt) {
        char* base = op ? ldsB(tt & 1, kh) : ldsA(tt & 1, kh);
        const bf16* g = op ? Bt : A;
        const int rowbase = op ? n0 : m0;
        const int ldr = op ? K : lda;
        #pragma unroll
        for (int l = 0; l < 2; ++l) {
            int q = tid + l * 512;
            int r = q >> 2;
            int cl = (q & 3) ^ ((r ^ (r >> 2)) & 3);
            const bf16* src = g + (size_t)(rowbase + r) * ldr + tt * 64 + kh * 32 + cl * 8;
            gload_lds16(src, (bf16*)(base + q * 16));
        }
    };
    auto rdA = [&](int d, int ks, int mi) -> bf16x8 {
        int row = wr * 128 + mi * 16 + (lane & 15);
        int ch = (lane >> 4) ^ ((row ^ (row >> 2)) & 3);
        return *(const bf16x8*)(ldsA(d, ks) + row * 64 + ch * 16);
    };
    auto rdB = [&](int d, int ks, int nj) -> bf16x8 {
        int row = wc * 64 + nj * 16 + (lane & 15);
        int ch = (lane >> 4) ^ ((row ^ (row >> 2)) & 3);
        return *(const bf16x8*)(ldsB(d, ks) + row * 64 + ch * 16);
    };

    f32x4 acc[8][4] = {};
    bf16x8 aF[4], bF[4];

    stage(0, 0, 0); stage(1, 0, 0); stage(0, 1, 0); stage(1, 1, 0);
    stage(0, 0, 1); stage(1, 0, 1);
    VMCNT(8);
    __builtin_amdgcn_s_barrier();
    __builtin_amdgcn_sched_barrier(0);

    #pragma unroll
    for (int t = 0; t < KT; ++t) {
        const int d = t & 1;
        #pragma unroll
        for (int mi = 0; mi < 4; ++mi) aF[mi] = rdA(d, 0, mi);
        #pragma unroll
        for (int nj = 0; nj < 4; ++nj) bF[nj] = rdB(d, 0, nj);
        if (t + 1 < KT) stage(0, 1, t + 1);
        __builtin_amdgcn_s_barrier();
        __builtin_amdgcn_s_setprio(1);
        #pragma unroll
        for (int mi = 0; mi < 4; ++mi)
            #pragma unroll
            for (int nj = 0; nj < 4; ++nj)
                acc[mi][nj] = __builtin_amdgcn_mfma_f32_16x16x32_bf16(aF[mi], bF[nj], acc[mi][nj], 0, 0, 0);
        __builtin_amdgcn_s_setprio(0);
        __builtin_amdgcn_s_barrier();
        #pragma unroll
        for (int mi = 0; mi < 4; ++mi) aF[mi] = rdA(d, 0, mi + 4);
        if (t + 1 < KT) stage(1, 1, t + 1);
        if (t + 1 < KT) { VMCNT(8); } else { VMCNT(0); }
        __builtin_amdgcn_s_barrier();
        __builtin_amdgcn_sched_barrier(0);
        __builtin_amdgcn_s_setprio(1);
        #pragma unroll
        for (int mi = 0; mi < 4; ++mi)
            #pragma unroll
            for (int nj = 0; nj < 4; ++nj)
                acc[mi + 4][nj] = __builtin_amdgcn_mfma_f32_16x16x32_bf16(aF[mi], bF[nj], acc[mi + 4][nj], 0, 0, 0);
        __builtin_amdgcn_s_setprio(0);
        __builtin_amdgcn_s_barrier();
        #pragma unroll
        for (int mi = 0; mi < 4; ++mi) aF[mi] = rdA(d, 1, mi);
        #pragma unroll
        for (int nj = 0; nj < 4; ++nj) bF[nj] = rdB(d, 1, nj);
        if (t + 2 < KT) stage(0, 0, t + 2);
        __builtin_amdgcn_s_barrier();
        __builtin_amdgcn_s_setprio(1);
        #pragma unroll
        for (int mi = 0; mi < 4; ++mi)
            #pragma unroll
            for (int nj = 0; nj < 4; ++nj)
                acc[mi][nj] = __builtin_amdgcn_mfma_f32_16x16x32_bf16(aF[mi], bF[nj], acc[mi][nj], 0, 0, 0);
        __builtin_amdgcn_s_setprio(0);
        __builtin_amdgcn_s_barrier();
        #pragma unroll
        for (int mi = 0; mi < 4; ++mi) aF[mi] = rdA(d, 1, mi + 4);
        if (t + 2 < KT) stage(1, 0, t + 2);
        if (t + 2 < KT)      { VMCNT(8); }
        else if (t + 1 < KT) { VMCNT(4); }
        __builtin_amdgcn_s_barrier();
        __builtin_amdgcn_sched_barrier(0);
        __builtin_amdgcn_s_setprio(1);
        #pragma unroll
        for (int mi = 0; mi < 4; ++mi)
            #pragma unroll
            for (int nj = 0; nj < 4; ++nj)
                acc[mi + 4][nj] = __builtin_amdgcn_mfma_f32_16x16x32_bf16(aF[mi], bF[nj], acc[mi + 4][nj], 0, 0, 0);
        __builtin_amdgcn_s_setprio(0);
        __builtin_amdgcn_s_barrier();
    }

    const int crow = (lane >> 4) * 4;
    const int ccol = lane & 15;
    #pragma unroll
    for (int mi = 0; mi < 8; ++mi)
        #pragma unroll
        for (int nj = 0; nj < 4; ++nj) {
            int gc = n0 + wc * 64 + nj * 16 + ccol;
            float bb = bias[gc];
            #pragma unroll
            for (int r = 0; r < 4; ++r) {
                int gr = m0 + wr * 128 + mi * 16 + crow + r;
                float val = acc[mi][nj][r] + bb;
                if (EPI == 1) val = val / (1.0f + expf(-val));
                stf(&out[(size_t)gr * ldo + gc], val);
            }
        }
}

// ---------------------------------------------------------------------------
// v channel transpose: Vt[c][b][ij(pad 224)] = v[b*196+ij][c]
__global__ __launch_bounds__(256) void k_vt(const bf16* __restrict__ uv,
                                            bf16* __restrict__ Vt) {
    const int c0 = blockIdx.x * 64;
    const int b  = blockIdx.y;
    const int tid = threadIdx.x;
    __shared__ bf16 t[196][66];
    for (int f = tid; f < 196 * 64; f += 256) {
        int ij = f >> 6, cl = f & 63;
        t[ij][cl] = uv[((size_t)b * 196 + ij) * 2048 + 1024 + c0 + cl];
    }
    __syncthreads();
    const bf16 z = __float2bfloat16(0.0f);
    for (int f = tid; f < 64 * 224; f += 256) {
        int cl = f / 224, ij = f - cl * 224;
        Vt[((size_t)(c0 + cl) * 64 + b) * 224 + ij] = (ij < 196) ? t[ij][cl] : z;
    }
}

// ---------------------------------------------------------------------------
// Per-channel Toeplitz GEMM, both halves via blockIdx.z.
__global__ __launch_bounds__(256) void k_convm(const bf16* __restrict__ Ab,
                                               const bf16* __restrict__ Vt,
                                               bf16* __restrict__ Yt) {
    __shared__ __align__(16) bf16 Ts[112 * 232];
    __shared__ bf16 As[736];
    const int mh = blockIdx.x;
    const int cl = blockIdx.y;
    const int c = (int)blockIdx.z * 512 + cl;
    const int tid = threadIdx.x;
    const int mbase = mh * 112;

    for (int e = tid; e < 729; e += 256)
        As[e] = Ab[(size_t)e * 1024 + c];
    __syncthreads();

    const bf16 z = __float2bfloat16(0.0f);
    if (tid < 224) {
        const int i = tid / 14, j = tid - i * 14;
        const bool kvalid = tid < 196;
        int p = mbase / 14, q = 0;
        for (int r = 0; r < 112; ++r) {
            bf16 val = z;
            if (kvalid && (mbase + r) < 196)
                val = As[(p - i + 13) * 27 + (q - j + 13)];
            Ts[r * 232 + tid] = val;
            if (++q == 14) { q = 0; ++p; }
        }
    }
    __syncthreads();

    const int lane = tid & 63;
    const int w = tid >> 6;
    const int lr = lane & 15;
    const int lk = (lane >> 4) * 8;
    const bf16* Vc = Vt + (size_t)c * 64 * 224;

    bf16x8 bfr[7];
    #pragma unroll
    for (int ks = 0; ks < 7; ++ks)
        bfr[ks] = *(const bf16x8*)&Vc[(size_t)(w * 16 + lr) * 224 + ks * 32 + lk];

    f32x4 acc[7] = {};
    #pragma unroll
    for (int ks = 0; ks < 7; ++ks)
        #pragma unroll
        for (int mi = 0; mi < 7; ++mi) {
            bf16x8 a = *(const bf16x8*)&Ts[(mi * 16 + lr) * 232 + ks * 32 + lk];
            acc[mi] = __builtin_amdgcn_mfma_f32_16x16x32_bf16(a, bfr[ks], acc[mi], 0, 0, 0);
        }

    const int crow = (lane >> 4) * 4;
    const int bb = w * 16 + (lane & 15);
    #pragma unroll
    for (int mi = 0; mi < 7; ++mi) {
        int pq = mbase + mi * 16 + crow;
        #pragma unroll
        for (int r = 0; r < 4; ++r)
            if (pq + r < 196)
                Yt[((size_t)c * 196 + pq + r) * 64 + bb] = __float2bfloat16(acc[mi][r]);
    }
}

// ---------------------------------------------------------------------------
__global__ __launch_bounds__(256) void k_gate(bf16* __restrict__ uv,
                                              const bf16* __restrict__ Yt) {
    const int pq = blockIdx.x;
    const int ct = blockIdx.y;
    const int cb = (int)blockIdx.z * 512;
    const int tid = threadIdx.x;
    __shared__ float t[64][65];
    for (int f = tid; f < 64 * 64; f += 256) {
        int cr = f >> 6, bcol = f & 63;
        t[cr][bcol] = __bfloat162float(Yt[((size_t)(cb + ct * 64 + cr) * 196 + pq) * 64 + bcol]);
    }
    __syncthreads();
    for (int f = tid; f < 64 * 64; f += 256) {
        int br = f >> 6, cc = f & 63;
        size_t row = (size_t)br * 196 + pq;
        int cglob = cb + ct * 64 + cc;
        float uu = __bfloat162float(uv[row * 2048 + cglob]);
        uv[row * 2048 + 1024 + cglob] = __float2bfloat16(t[cc][br] * uu);
    }
}

// ---------------------------------------------------------------------------
extern "C" void kernel_launch(void* const* d_in, const int* in_sizes, int n_in,
                              void* d_out, int out_size, void* d_ws, size_t ws_size,
                              hipStream_t stream) {
    const float* x    = (const float*)d_in[0];
    const float* Wu   = (const float*)d_in[3];
    const float* bu   = (const float*)d_in[4];
    const float* Wv   = (const float*)d_in[5];
    const float* bv   = (const float*)d_in[6];
    const float* Wo   = (const float*)d_in[7];
    const float* bo   = (const float*)d_in[8];
    const float* rpw  = (const float*)d_in[9];
    const float* rpb  = (const float*)d_in[10];
    const float* w1   = (const float*)d_in[11];
    const float* b1   = (const float*)d_in[12];
    const float* w2   = (const float*)d_in[13];
    const float* b2   = (const float*)d_in[14];
    const float* w3   = (const float*)d_in[15];
    const float* b3   = (const float*)d_in[16];
    const float* wOut = (const float*)d_in[17];
    const float* bOut = (const float*)d_in[18];

    char* ws = (char*)d_ws;
    size_t off = 0;
    auto take = [&](size_t bytes) { char* p = ws + off; off += (bytes + 255) & ~size_t(255); return p; };
    bf16*  rnA    = (bf16*)take((size_t)768 * 512 * 2);
    bf16*  rnB    = (bf16*)take((size_t)768 * 512 * 2);
    float* p1     = (float*)take((size_t)768 * 8 * 4);
    float* p2     = (float*)take((size_t)768 * 8 * 4);
    float* p3     = (float*)take((size_t)768 * 8 * 4);
    bf16*  Ab     = (bf16*)take((size_t)RPOS * 1024 * 2);
    bf16*  xb     = (bf16*)take((size_t)ROWS * EE * 2);
    bf16*  WuvT   = (bf16*)take((size_t)2048 * 512 * 2);
    bf16*  WoT    = (bf16*)take((size_t)512 * 1024 * 2);
    bf16*  w1T    = (bf16*)take((size_t)512 * 512 * 2);
    bf16*  w2T    = (bf16*)take((size_t)512 * 512 * 2);
    bf16*  w3T    = (bf16*)take((size_t)512 * 512 * 2);
    bf16*  wOutT  = (bf16*)take((size_t)1024 * 512 * 2);
    float* biasUv = (float*)take(2048 * 4);
    bf16*  uvb    = (bf16*)take((size_t)ROWS * 2048 * 2);
    bf16*  Vt     = (bf16*)take((size_t)1024 * 64 * 224 * 2);
    bf16*  Yt     = (bf16*)take((size_t)1024 * 196 * 64 * 2);

    // --- all prep (incl. RPE pos+norm) in one dispatch ---
    k_prep<<<9825, 256, 0, stream>>>(Wu, Wv, Wo, w1, w2, w3, wOut, bu, bv, x,
                                     rpw, rpb,
                                     WuvT, WoT, w1T, w2T, w3T, wOutT, biasUv, xb, rnA);

    // --- RPE MLP: 4 GEMMs with fused norm bookkeeping (double-buffered) ---
    k_rpe_gemm<0, 0><<<dim3(8, 12), 256, 0, stream>>>(rnA, w1T, b1, nullptr, p1, rnB, RPOS, 512, 512);
    k_rpe_gemm<1, 0><<<dim3(8, 12), 256, 0, stream>>>(rnB, w2T, b2, p1, p2, rnA, RPOS, 512, 512);
    k_rpe_gemm<1, 0><<<dim3(8, 12), 256, 0, stream>>>(rnA, w3T, b3, p2, p3, rnB, RPOS, 512, 512);
    k_rpe_gemm<1, 2><<<dim3(16, 12), 256, 0, stream>>>(rnB, wOutT, bOut, p3, nullptr, Ab, RPOS, 1024, 512);

    // --- uv = silu(x @ [Wu|Wv] + [bu|bv])  (8-phase 256^2, KT=8) ---
    k_mgemm8<8, 1, bf16><<<392, 512, 0, stream>>>(xb, 512, WuvT, biasUv, uvb, 2048, 8);

    // --- v -> channel-major Vt ---
    k_vt<<<dim3(16, 64), 256, 0, stream>>>(uvb, Vt);

    // --- Toeplitz conv (MFMA) + gating ---
    k_convm<<<dim3(2, 512, 2), 256, 0, stream>>>(Ab, Vt, Yt);
    k_gate<<<dim3(196, 8, 2), 256, 0, stream>>>(uvb, Yt);

    // --- out = g @ Wo + bo  (m97 128^2, grid 392) ---
    k_mgemm<0, float><<<dim3(4, 98), 256, 0, stream>>>(uvb + 1024, 2048, WoT, bo,
                                                       (float*)d_out, 512, ROWS, 512, 1024);
}

// Round 17
// 198.319 us; speedup vs baseline: 1.0975x; 1.0824x over previous
//
#include <hip/hip_runtime.h>
#include <hip/hip_bf16.h>

typedef __hip_bfloat16 bf16;
typedef __attribute__((ext_vector_type(8))) short bf16x8;
typedef __attribute__((ext_vector_type(4))) float f32x4;

constexpr int NB    = 64;
constexpr int EE    = 512;
constexpr int RPOS  = 27 * 27;       // 729
constexpr int ROWS  = NB * 14 * 14;  // 12544
constexpr int UVNWG = 392;           // uv GEMM tiles (49 x 8)

#define RMS_EPS 1e-6f
#define GAMMA_LOG2 (-0.00144344319f)   // log2(0.999)

__device__ __forceinline__ void  stf(float* p, float v) { *p = v; }
__device__ __forceinline__ void  stf(bf16* p, float v)  { *p = __float2bfloat16(v); }

__device__ __forceinline__ void gload_lds16(const bf16* g, bf16* l) {
    __builtin_amdgcn_global_load_lds(
        (const __attribute__((address_space(1))) void*)g,
        (__attribute__((address_space(3))) void*)l, 16, 0, 0);
}

#define VMCNT(n) asm volatile("s_waitcnt vmcnt(" #n ")" ::: "memory")

// ---------------------------------------------------------------------------
// One-shot prep: 7 weight transposes, bias concat, x -> bf16, RPE pos+norm.
__global__ __launch_bounds__(256) void k_prep(const float* __restrict__ Wu,
                                              const float* __restrict__ Wv,
                                              const float* __restrict__ Wo,
                                              const float* __restrict__ w1,
                                              const float* __restrict__ w2,
                                              const float* __restrict__ w3,
                                              const float* __restrict__ wOut,
                                              const float* __restrict__ bu,
                                              const float* __restrict__ bv,
                                              const float* __restrict__ x,
                                              const float* __restrict__ rpw,
                                              const float* __restrict__ rpb,
                                              bf16* __restrict__ WuvT,
                                              bf16* __restrict__ WoT,
                                              bf16* __restrict__ w1T,
                                              bf16* __restrict__ w2T,
                                              bf16* __restrict__ w3T,
                                              bf16* __restrict__ wOutT,
                                              float* __restrict__ biasUv,
                                              bf16* __restrict__ xb,
                                              bf16* __restrict__ rnA) {
    __shared__ float t[32][33];
    __shared__ float ps[4];
    const int tid = threadIdx.x;
    int b = blockIdx.x;

    const float* src = nullptr; bf16* dst = nullptr; int R = 0, C = 0, nbx = 0;
    if (b < 512)        { src = Wu;   dst = WuvT;                      R = 512;  C = 1024; nbx = 32; }
    else if (b < 1024)  { b -= 512;   src = Wv; dst = WuvT + (size_t)1024 * 512; R = 512; C = 1024; nbx = 32; }
    else if (b < 1536)  { b -= 1024;  src = Wo;   dst = WoT;           R = 1024; C = 512;  nbx = 16; }
    else if (b < 1792)  { b -= 1536;  src = w1;   dst = w1T;           R = 512;  C = 512;  nbx = 16; }
    else if (b < 2048)  { b -= 1792;  src = w2;   dst = w2T;           R = 512;  C = 512;  nbx = 16; }
    else if (b < 2304)  { b -= 2048;  src = w3;   dst = w3T;           R = 512;  C = 512;  nbx = 16; }
    else if (b < 2816)  { b -= 2304;  src = wOut; dst = wOutT;         R = 512;  C = 1024; nbx = 32; }
    else if (b < 2824) {               // bias concat
        int c = (b - 2816) * 256 + tid;
        if (c < 2048) biasUv[c] = (c < 1024) ? bu[c] : bv[c - 1024];
        return;
    } else if (b < 9096) {             // x -> bf16
        int i = (b - 2824) * 256 + tid;
        float4 v = *(const float4*)&x[(size_t)i * 4];
        bf16* d = &xb[(size_t)i * 4];
        d[0] = __float2bfloat16(v.x);
        d[1] = __float2bfloat16(v.y);
        d[2] = __float2bfloat16(v.z);
        d[3] = __float2bfloat16(v.w);
        return;
    } else {                           // RPE pos + rmsnorm + relu: 729 blocks
        int p = b - 9096;
        float ii = (float)(p / 27 - 13);
        float jj = (float)(p % 27 - 13);
        int c0 = tid, c1 = tid + 256;
        float v0 = ii * rpw[c0] + jj * rpw[512 + c0] + rpb[c0];
        float v1 = ii * rpw[c1] + jj * rpw[512 + c1] + rpb[c1];
        float s = v0 * v0 + v1 * v1;
        #pragma unroll
        for (int off = 32; off; off >>= 1) s += __shfl_down(s, off, 64);
        if ((tid & 63) == 0) ps[tid >> 6] = s;
        __syncthreads();
        float tot = ps[0] + ps[1] + ps[2] + ps[3];
        float scale = rsqrtf(tot * (1.0f / 512.0f) + RMS_EPS);
        rnA[(size_t)p * 512 + c0] = __float2bfloat16(fmaxf(v0 * scale, 0.0f));
        rnA[(size_t)p * 512 + c1] = __float2bfloat16(fmaxf(v1 * scale, 0.0f));
        return;
    }
    int bx = (b % nbx) * 32;
    int by = (b / nbx) * 32;
    int tx = tid & 31, ty = tid >> 5;
    #pragma unroll
    for (int i = 0; i < 4; ++i)
        t[ty + i * 8][tx] = src[(size_t)(by + ty + i * 8) * C + bx + tx];
    __syncthreads();
    #pragma unroll
    for (int i = 0; i < 4; ++i)
        dst[(size_t)(bx + ty + i * 8) * R + by + tx] = __float2bfloat16(t[tx][ty + i * 8]);
}

// ---------------------------------------------------------------------------
// RPE-layer GEMM body (64x64 tile, BK=32, 4 waves of a 256-lane group),
// double-buffered staging with counted vmcnt (R16-proven).
// As/Bs: each [2][2048] bf16 in the caller's LDS. tid in [0,256).
template <int SCALE_IN, int EPI>
__device__ __forceinline__ void rpe_body(const bf16* __restrict__ A,
                                         const bf16* __restrict__ Bt,
                                         const float* __restrict__ bias,
                                         const float* __restrict__ pIn,
                                         float* __restrict__ pOut,
                                         bf16* __restrict__ out,
                                         int bx, int by, int M, int N, int K,
                                         bf16* As, bf16* Bs, int tid) {
    const int m0 = by * 64;
    const int n0 = bx * 64;
    const int lane = tid & 63;
    const int w = (tid >> 6) & 3;
    const int lr = lane & 15;
    const int lk = (lane >> 4) * 8;
    const int row = tid >> 2;
    const int seg = (tid & 3) * 8;

    f32x4 acc[4] = {};
    const int KT = K >> 5;

    gload_lds16(&A[(size_t)(m0 + row) * K + seg], &As[tid * 8]);
    gload_lds16(&Bt[(size_t)(n0 + row) * K + seg], &Bs[tid * 8]);
    for (int t = 0; t < KT; ++t) {
        const int d = t & 1;
        if (t + 1 < KT) {
            gload_lds16(&A[(size_t)(m0 + row) * K + (t + 1) * 32 + seg], &As[(d ^ 1) * 2048 + tid * 8]);
            gload_lds16(&Bt[(size_t)(n0 + row) * K + (t + 1) * 32 + seg], &Bs[(d ^ 1) * 2048 + tid * 8]);
            VMCNT(2);
        } else {
            VMCNT(0);
        }
        __builtin_amdgcn_s_barrier();
        __builtin_amdgcn_sched_barrier(0);
        bf16x8 af = *(const bf16x8*)&As[d * 2048 + (w * 16 + lr) * 32 + lk];
        #pragma unroll
        for (int j = 0; j < 4; ++j) {
            bf16x8 bf = *(const bf16x8*)&Bs[d * 2048 + (j * 16 + lr) * 32 + lk];
            acc[j] = __builtin_amdgcn_mfma_f32_16x16x32_bf16(af, bf, acc[j], 0, 0, 0);
        }
        __builtin_amdgcn_s_barrier();
    }

    const int crow = (lane >> 4) * 4;
    const int ccol = lane & 15;
    float sc[4];
    #pragma unroll
    for (int r = 0; r < 4; ++r) {
        sc[r] = 1.0f;
        if (SCALE_IN) {
            int gr = m0 + w * 16 + crow + r;
            if (gr < M) {
                const float* pp = &pIn[(size_t)gr * 8];
                float s8 = pp[0] + pp[1] + pp[2] + pp[3] + pp[4] + pp[5] + pp[6] + pp[7];
                sc[r] = rsqrtf(s8 * (1.0f / 512.0f) + RMS_EPS);
            }
        }
    }
    float rowsq[4] = {0.f, 0.f, 0.f, 0.f};
    #pragma unroll
    for (int j = 0; j < 4; ++j) {
        int gc = n0 + j * 16 + ccol;
        float bb = bias[gc];
        #pragma unroll
        for (int r = 0; r < 4; ++r) {
            int gr = m0 + w * 16 + crow + r;
            float val = acc[j][r] * sc[r] + bb;
            if (EPI == 0) {
                rowsq[r] += val * val;
                if (gr < M) out[(size_t)gr * N + gc] = __float2bfloat16(fmaxf(val, 0.0f));
            } else {
                if (gr < M) {
                    int i = gr / 27, jj = gr % 27;
                    float decay = exp2f((float)(abs(i - 13) + abs(jj - 13)) * GAMMA_LOG2);
                    out[(size_t)gr * N + gc] = __float2bfloat16(val * decay);
                }
            }
        }
    }
    if (EPI == 0) {
        #pragma unroll
        for (int r = 0; r < 4; ++r) {
            #pragma unroll
            for (int m = 1; m < 16; m <<= 1) rowsq[r] += __shfl_xor(rowsq[r], m, 64);
        }
        if ((lane & 15) == 0) {
            #pragma unroll
            for (int r = 0; r < 4; ++r) {
                int gr = m0 + w * 16 + crow + r;
                if (gr < M) pOut[(size_t)gr * 8 + bx] = rowsq[r];
            }
        }
    }
}

// Standalone 256-thread wrapper (L3, L4).
template <int SCALE_IN, int EPI>
__global__ __launch_bounds__(256) void k_rpe_gemm(const bf16* __restrict__ A,
                                                  const bf16* __restrict__ Bt,
                                                  const float* __restrict__ bias,
                                                  const float* __restrict__ pIn,
                                                  float* __restrict__ pOut,
                                                  bf16* __restrict__ out,
                                                  int M, int N, int K) {
    __shared__ bf16 As[2][2048];
    __shared__ bf16 Bs[2][2048];
    rpe_body<SCALE_IN, EPI>(A, Bt, bias, pIn, pOut, out,
                            blockIdx.x, blockIdx.y, M, N, K,
                            &As[0][0], &Bs[0][0], threadIdx.x);
}

// ---------------------------------------------------------------------------
// m97-structure 128x128 MFMA GEMM (out GEMM; multi-block/CU).
template <int EPI, typename TO>
__global__ __launch_bounds__(256) void k_mgemm(const bf16* __restrict__ A, int lda,
                                               const bf16* __restrict__ Bt,
                                               const float* __restrict__ bias,
                                               TO* __restrict__ out, int ldo,
                                               int M, int N, int K) {
    __shared__ bf16 As[128 * 32];
    __shared__ bf16 Bs[128 * 32];
    const int tid = threadIdx.x;
    const int m0 = blockIdx.y * 128;
    const int n0 = blockIdx.x * 128;
    const int lane = tid & 63;
    const int w = tid >> 6;
    const int wr = (w >> 1) * 64;
    const int wc = (w & 1) * 64;
    const int lr = lane & 15;
    const int lk = (lane >> 4) * 8;

    f32x4 acc[4][4] = {};

    for (int k0 = 0; k0 < K; k0 += 32) {
        #pragma unroll
        for (int t = 0; t < 2; ++t) {
            int flat = t * 256 + tid;
            int row = flat >> 2;
            int seg = (flat & 3) * 8;
            gload_lds16(&A[(size_t)(m0 + row) * lda + k0 + seg], &As[flat * 8]);
            gload_lds16(&Bt[(size_t)(n0 + row) * K + k0 + seg], &Bs[flat * 8]);
        }
        __syncthreads();
        bf16x8 af[4], bf[4];
        #pragma unroll
        for (int i = 0; i < 4; ++i) {
            af[i] = *(const bf16x8*)&As[(wr + i * 16 + lr) * 32 + lk];
            bf[i] = *(const bf16x8*)&Bs[(wc + i * 16 + lr) * 32 + lk];
        }
        #pragma unroll
        for (int i = 0; i < 4; ++i)
            #pragma unroll
            for (int j = 0; j < 4; ++j)
                acc[i][j] = __builtin_amdgcn_mfma_f32_16x16x32_bf16(af[i], bf[j], acc[i][j], 0, 0, 0);
        __syncthreads();
    }

    const int crow = (lane >> 4) * 4;
    const int ccol = lane & 15;
    #pragma unroll
    for (int i = 0; i < 4; ++i)
        #pragma unroll
        for (int j = 0; j < 4; ++j) {
            int gc = n0 + wc + j * 16 + ccol;
            float bb = bias[gc];
            #pragma unroll
            for (int r = 0; r < 4; ++r) {
                int gr = m0 + wr + i * 16 + crow + r;
                float val = acc[i][j][r] + bb;
                if (EPI == 1) val = val / (1.0f + expf(-val));
                stf(&out[(size_t)gr * ldo + gc], val);
            }
        }
}

// ---------------------------------------------------------------------------
// Combined dispatch: blocks [0,392) run the frozen 8-phase 256^2 uv GEMM;
// blocks [392,392+48) run RPE layer-1 (two 64x64 tiles per 512-thr block),
// filling the CUs idle in uv's second scheduling round.
__global__ __launch_bounds__(512, 2) void k_uv_l1(const bf16* __restrict__ A, int lda,
                                                  const bf16* __restrict__ Bt,
                                                  const float* __restrict__ bias,
                                                  bf16* __restrict__ out, int ldo,
                                                  int nb /* N/256 */,
                                                  const bf16* __restrict__ rA,
                                                  const bf16* __restrict__ w1T,
                                                  const float* __restrict__ b1,
                                                  float* __restrict__ p1,
                                                  bf16* __restrict__ rB) {
    constexpr int KT = 8;
    constexpr int K = KT * 64;
    __shared__ __align__(16) char lds[131072];

    const int tid = threadIdx.x;

    if (blockIdx.x >= UVNWG) {
        // --- RPE L1: two tiles per block, one per 256-thread half ---
        const int orig = (blockIdx.x - UVNWG) * 2 + (tid >> 8);   // 0..95
        const int half = tid >> 8;
        bf16* As = (bf16*)(lds + half * 32768);
        bf16* Bs = (bf16*)(lds + half * 32768 + 8192);
        rpe_body<0, 0>(rA, w1T, b1, nullptr, p1, rB,
                       orig & 7, orig >> 3, RPOS, 512, 512, As, Bs, tid & 255);
        return;
    }

    const int lane = tid & 63;
    const int wid = tid >> 6;
    const int wr = wid >> 2;
    const int wc = wid & 3;

    // XCD swizzle over the uv sub-grid (392 % 8 == 0 -> bijective)
    int wgid = blockIdx.x;
    {
        int cpx = UVNWG >> 3;          // 49
        wgid = (wgid & 7) * cpx + (wgid >> 3);
    }
    const int m0 = (wgid / nb) * 256;
    const int n0 = (wgid % nb) * 256;

    auto ldsA = [&](int d, int kh) -> char* { return (char*)lds + d * 32768 + kh * 16384; };
    auto ldsB = [&](int d, int kh) -> char* { return (char*)lds + 65536 + d * 32768 + kh * 16384; };

    auto stage = [&](int op, int kh, int tt) {
        char* base = op ? ldsB(tt & 1, kh) : ldsA(tt & 1, kh);
        const bf16* g = op ? Bt : A;
        const int rowbase = op ? n0 : m0;
        const int ldr = op ? K : lda;
        #pragma unroll
        for (int l = 0; l < 2; ++l) {
            int q = tid + l * 512;
            int r = q >> 2;
            int cl = (q & 3) ^ ((r ^ (r >> 2)) & 3);
            const bf16* src = g + (size_t)(rowbase + r) * ldr + tt * 64 + kh * 32 + cl * 8;
            gload_lds16(src, (bf16*)(base + q * 16));
        }
    };
    auto rdA = [&](int d, int ks, int mi) -> bf16x8 {
        int row = wr * 128 + mi * 16 + (lane & 15);
        int ch = (lane >> 4) ^ ((row ^ (row >> 2)) & 3);
        return *(const bf16x8*)(ldsA(d, ks) + row * 64 + ch * 16);
    };
    auto rdB = [&](int d, int ks, int nj) -> bf16x8 {
        int row = wc * 64 + nj * 16 + (lane & 15);
        int ch = (lane >> 4) ^ ((row ^ (row >> 2)) & 3);
        return *(const bf16x8*)(ldsB(d, ks) + row * 64 + ch * 16);
    };

    f32x4 acc[8][4] = {};
    bf16x8 aF[4], bF[4];

    stage(0, 0, 0); stage(1, 0, 0); stage(0, 1, 0); stage(1, 1, 0);
    stage(0, 0, 1); stage(1, 0, 1);
    VMCNT(8);
    __builtin_amdgcn_s_barrier();
    __builtin_amdgcn_sched_barrier(0);

    #pragma unroll
    for (int t = 0; t < KT; ++t) {
        const int d = t & 1;
        #pragma unroll
        for (int mi = 0; mi < 4; ++mi) aF[mi] = rdA(d, 0, mi);
        #pragma unroll
        for (int nj = 0; nj < 4; ++nj) bF[nj] = rdB(d, 0, nj);
        if (t + 1 < KT) stage(0, 1, t + 1);
        __builtin_amdgcn_s_barrier();
        __builtin_amdgcn_s_setprio(1);
        #pragma unroll
        for (int mi = 0; mi < 4; ++mi)
            #pragma unroll
            for (int nj = 0; nj < 4; ++nj)
                acc[mi][nj] = __builtin_amdgcn_mfma_f32_16x16x32_bf16(aF[mi], bF[nj], acc[mi][nj], 0, 0, 0);
        __builtin_amdgcn_s_setprio(0);
        __builtin_amdgcn_s_barrier();
        #pragma unroll
        for (int mi = 0; mi < 4; ++mi) aF[mi] = rdA(d, 0, mi + 4);
        if (t + 1 < KT) stage(1, 1, t + 1);
        if (t + 1 < KT) { VMCNT(8); } else { VMCNT(0); }
        __builtin_amdgcn_s_barrier();
        __builtin_amdgcn_sched_barrier(0);
        __builtin_amdgcn_s_setprio(1);
        #pragma unroll
        for (int mi = 0; mi < 4; ++mi)
            #pragma unroll
            for (int nj = 0; nj < 4; ++nj)
                acc[mi + 4][nj] = __builtin_amdgcn_mfma_f32_16x16x32_bf16(aF[mi], bF[nj], acc[mi + 4][nj], 0, 0, 0);
        __builtin_amdgcn_s_setprio(0);
        __builtin_amdgcn_s_barrier();
        #pragma unroll
        for (int mi = 0; mi < 4; ++mi) aF[mi] = rdA(d, 1, mi);
        #pragma unroll
        for (int nj = 0; nj < 4; ++nj) bF[nj] = rdB(d, 1, nj);
        if (t + 2 < KT) stage(0, 0, t + 2);
        __builtin_amdgcn_s_barrier();
        __builtin_amdgcn_s_setprio(1);
        #pragma unroll
        for (int mi = 0; mi < 4; ++mi)
            #pragma unroll
            for (int nj = 0; nj < 4; ++nj)
                acc[mi][nj] = __builtin_amdgcn_mfma_f32_16x16x32_bf16(aF[mi], bF[nj], acc[mi][nj], 0, 0, 0);
        __builtin_amdgcn_s_setprio(0);
        __builtin_amdgcn_s_barrier();
        #pragma unroll
        for (int mi = 0; mi < 4; ++mi) aF[mi] = rdA(d, 1, mi + 4);
        if (t + 2 < KT) stage(1, 0, t + 2);
        if (t + 2 < KT)      { VMCNT(8); }
        else if (t + 1 < KT) { VMCNT(4); }
        __builtin_amdgcn_s_barrier();
        __builtin_amdgcn_sched_barrier(0);
        __builtin_amdgcn_s_setprio(1);
        #pragma unroll
        for (int mi = 0; mi < 4; ++mi)
            #pragma unroll
            for (int nj = 0; nj < 4; ++nj)
                acc[mi + 4][nj] = __builtin_amdgcn_mfma_f32_16x16x32_bf16(aF[mi], bF[nj], acc[mi + 4][nj], 0, 0, 0);
        __builtin_amdgcn_s_setprio(0);
        __builtin_amdgcn_s_barrier();
    }

    const int crow = (lane >> 4) * 4;
    const int ccol = lane & 15;
    #pragma unroll
    for (int mi = 0; mi < 8; ++mi)
        #pragma unroll
        for (int nj = 0; nj < 4; ++nj) {
            int gc = n0 + wc * 64 + nj * 16 + ccol;
            float bb = bias[gc];
            #pragma unroll
            for (int r = 0; r < 4; ++r) {
                int gr = m0 + wr * 128 + mi * 16 + crow + r;
                float val = acc[mi][nj][r] + bb;
                val = val / (1.0f + expf(-val));
                stf(&out[(size_t)gr * ldo + gc], val);
            }
        }
}

// ---------------------------------------------------------------------------
// Combined dispatch: blocks [0,1024) do the v channel transpose
// (Vt[c][b][ij pad 224] = v[b*196+ij][c]); blocks [1024,1024+96) run RPE L2.
__global__ __launch_bounds__(256) void k_vt_l2(const bf16* __restrict__ uv,
                                               bf16* __restrict__ Vt,
                                               const bf16* __restrict__ rB,
                                               const bf16* __restrict__ w2T,
                                               const float* __restrict__ b2,
                                               const float* __restrict__ p1,
                                               float* __restrict__ p2,
                                               bf16* __restrict__ rA) {
    __shared__ __align__(16) char lraw[25872 > 16384 ? 25872 : 16384];
    const int tid = threadIdx.x;

    if (blockIdx.x >= 1024) {
        const int orig = blockIdx.x - 1024;     // 0..95
        bf16* As = (bf16*)lraw;
        bf16* Bs = (bf16*)(lraw + 8192);
        rpe_body<1, 0>(rB, w2T, b2, p1, p2, rA,
                       orig & 7, orig >> 3, RPOS, 512, 512, As, Bs, tid);
        return;
    }

    typedef bf16 row66[66];
    row66* t = (row66*)lraw;
    const int c0 = (blockIdx.x & 15) * 64;
    const int b  = blockIdx.x >> 4;
    for (int f = tid; f < 196 * 64; f += 256) {
        int ij = f >> 6, cl = f & 63;
        t[ij][cl] = uv[((size_t)b * 196 + ij) * 2048 + 1024 + c0 + cl];
    }
    __syncthreads();
    const bf16 z = __float2bfloat16(0.0f);
    for (int f = tid; f < 64 * 224; f += 256) {
        int cl = f / 224, ij = f - cl * 224;
        Vt[((size_t)(c0 + cl) * 64 + b) * 224 + ij] = (ij < 196) ? t[ij][cl] : z;
    }
}

// ---------------------------------------------------------------------------
// Per-channel Toeplitz GEMM, both halves via blockIdx.z.
__global__ __launch_bounds__(256) void k_convm(const bf16* __restrict__ Ab,
                                               const bf16* __restrict__ Vt,
                                               bf16* __restrict__ Yt) {
    __shared__ __align__(16) bf16 Ts[112 * 232];
    __shared__ bf16 As[736];
    const int mh = blockIdx.x;
    const int cl = blockIdx.y;
    const int c = (int)blockIdx.z * 512 + cl;
    const int tid = threadIdx.x;
    const int mbase = mh * 112;

    for (int e = tid; e < 729; e += 256)
        As[e] = Ab[(size_t)e * 1024 + c];
    __syncthreads();

    const bf16 z = __float2bfloat16(0.0f);
    if (tid < 224) {
        const int i = tid / 14, j = tid - i * 14;
        const bool kvalid = tid < 196;
        int p = mbase / 14, q = 0;
        for (int r = 0; r < 112; ++r) {
            bf16 val = z;
            if (kvalid && (mbase + r) < 196)
                val = As[(p - i + 13) * 27 + (q - j + 13)];
            Ts[r * 232 + tid] = val;
            if (++q == 14) { q = 0; ++p; }
        }
    }
    __syncthreads();

    const int lane = tid & 63;
    const int w = tid >> 6;
    const int lr = lane & 15;
    const int lk = (lane >> 4) * 8;
    const bf16* Vc = Vt + (size_t)c * 64 * 224;

    bf16x8 bfr[7];
    #pragma unroll
    for (int ks = 0; ks < 7; ++ks)
        bfr[ks] = *(const bf16x8*)&Vc[(size_t)(w * 16 + lr) * 224 + ks * 32 + lk];

    f32x4 acc[7] = {};
    #pragma unroll
    for (int ks = 0; ks < 7; ++ks)
        #pragma unroll
        for (int mi = 0; mi < 7; ++mi) {
            bf16x8 a = *(const bf16x8*)&Ts[(mi * 16 + lr) * 232 + ks * 32 + lk];
            acc[mi] = __builtin_amdgcn_mfma_f32_16x16x32_bf16(a, bfr[ks], acc[mi], 0, 0, 0);
        }

    const int crow = (lane >> 4) * 4;
    const int bb = w * 16 + (lane & 15);
    #pragma unroll
    for (int mi = 0; mi < 7; ++mi) {
        int pq = mbase + mi * 16 + crow;
        #pragma unroll
        for (int r = 0; r < 4; ++r)
            if (pq + r < 196)
                Yt[((size_t)c * 196 + pq + r) * 64 + bb] = __float2bfloat16(acc[mi][r]);
    }
}

// ---------------------------------------------------------------------------
__global__ __launch_bounds__(256) void k_gate(bf16* __restrict__ uv,
                                              const bf16* __restrict__ Yt) {
    const int pq = blockIdx.x;
    const int ct = blockIdx.y;
    const int cb = (int)blockIdx.z * 512;
    const int tid = threadIdx.x;
    __shared__ float t[64][65];
    for (int f = tid; f < 64 * 64; f += 256) {
        int cr = f >> 6, bcol = f & 63;
        t[cr][bcol] = __bfloat162float(Yt[((size_t)(cb + ct * 64 + cr) * 196 + pq) * 64 + bcol]);
    }
    __syncthreads();
    for (int f = tid; f < 64 * 64; f += 256) {
        int br = f >> 6, cc = f & 63;
        size_t row = (size_t)br * 196 + pq;
        int cglob = cb + ct * 64 + cc;
        float uu = __bfloat162float(uv[row * 2048 + cglob]);
        uv[row * 2048 + 1024 + cglob] = __float2bfloat16(t[cc][br] * uu);
    }
}

// ---------------------------------------------------------------------------
extern "C" void kernel_launch(void* const* d_in, const int* in_sizes, int n_in,
                              void* d_out, int out_size, void* d_ws, size_t ws_size,
                              hipStream_t stream) {
    const float* x    = (const float*)d_in[0];
    const float* Wu   = (const float*)d_in[3];
    const float* bu   = (const float*)d_in[4];
    const float* Wv   = (const float*)d_in[5];
    const float* bv   = (const float*)d_in[6];
    const float* Wo   = (const float*)d_in[7];
    const float* bo   = (const float*)d_in[8];
    const float* rpw  = (const float*)d_in[9];
    const float* rpb  = (const float*)d_in[10];
    const float* w1   = (const float*)d_in[11];
    const float* b1   = (const float*)d_in[12];
    const float* w2   = (const float*)d_in[13];
    const float* b2   = (const float*)d_in[14];
    const float* w3   = (const float*)d_in[15];
    const float* b3   = (const float*)d_in[16];
    const float* wOut = (const float*)d_in[17];
    const float* bOut = (const float*)d_in[18];

    char* ws = (char*)d_ws;
    size_t off = 0;
    auto take = [&](size_t bytes) { char* p = ws + off; off += (bytes + 255) & ~size_t(255); return p; };
    bf16*  rnA    = (bf16*)take((size_t)768 * 512 * 2);
    bf16*  rnB    = (bf16*)take((size_t)768 * 512 * 2);
    float* p1     = (float*)take((size_t)768 * 8 * 4);
    float* p2     = (float*)take((size_t)768 * 8 * 4);
    float* p3     = (float*)take((size_t)768 * 8 * 4);
    bf16*  Ab     = (bf16*)take((size_t)RPOS * 1024 * 2);
    bf16*  xb     = (bf16*)take((size_t)ROWS * EE * 2);
    bf16*  WuvT   = (bf16*)take((size_t)2048 * 512 * 2);
    bf16*  WoT    = (bf16*)take((size_t)512 * 1024 * 2);
    bf16*  w1T    = (bf16*)take((size_t)512 * 512 * 2);
    bf16*  w2T    = (bf16*)take((size_t)512 * 512 * 2);
    bf16*  w3T    = (bf16*)take((size_t)512 * 512 * 2);
    bf16*  wOutT  = (bf16*)take((size_t)1024 * 512 * 2);
    float* biasUv = (float*)take(2048 * 4);
    bf16*  uvb    = (bf16*)take((size_t)ROWS * 2048 * 2);
    bf16*  Vt     = (bf16*)take((size_t)1024 * 64 * 224 * 2);
    bf16*  Yt     = (bf16*)take((size_t)1024 * 196 * 64 * 2);

    // --- all prep (incl. RPE pos+norm) ---
    k_prep<<<9825, 256, 0, stream>>>(Wu, Wv, Wo, w1, w2, w3, wOut, bu, bv, x,
                                     rpw, rpb,
                                     WuvT, WoT, w1T, w2T, w3T, wOutT, biasUv, xb, rnA);

    // --- uv GEMM + RPE L1 co-dispatched (440 blocks) ---
    k_uv_l1<<<UVNWG + 48, 512, 0, stream>>>(xb, 512, WuvT, biasUv, uvb, 2048, 8,
                                            rnA, w1T, b1, p1, rnB);

    // --- v transpose + RPE L2 co-dispatched (1120 blocks) ---
    k_vt_l2<<<1120, 256, 0, stream>>>(uvb, Vt, rnB, w2T, b2, p1, p2, rnA);

    // --- RPE L3, L4 ---
    k_rpe_gemm<1, 0><<<dim3(8, 12), 256, 0, stream>>>(rnA, w3T, b3, p2, p3, rnB, RPOS, 512, 512);
    k_rpe_gemm<1, 2><<<dim3(16, 12), 256, 0, stream>>>(rnB, wOutT, bOut, p3, nullptr, Ab, RPOS, 1024, 512);

    // --- Toeplitz conv (MFMA) + gating ---
    k_convm<<<dim3(2, 512, 2), 256, 0, stream>>>(Ab, Vt, Yt);
    k_gate<<<dim3(196, 8, 2), 256, 0, stream>>>(uvb, Yt);

    // --- out = g @ Wo + bo  (m97 128^2, grid 392) ---
    k_mgemm<0, float><<<dim3(4, 98), 256, 0, stream>>>(uvb + 1024, 2048, WoT, bo,
                                                       (float*)d_out, 512, ROWS, 512, 1024);
}

// Round 18
// 192.034 us; speedup vs baseline: 1.1334x; 1.0327x over previous
//
#include <hip/hip_runtime.h>
#include <hip/hip_bf16.h>

typedef __hip_bfloat16 bf16;
typedef __attribute__((ext_vector_type(8))) short bf16x8;
typedef __attribute__((ext_vector_type(4))) float f32x4;

constexpr int NB    = 64;
constexpr int EE    = 512;
constexpr int RPOS  = 27 * 27;       // 729
constexpr int ROWS  = NB * 14 * 14;  // 12544
constexpr int UVNWG = 392;           // uv GEMM tiles (49 x 8)

#define RMS_EPS 1e-6f
#define GAMMA_LOG2 (-0.00144344319f)   // log2(0.999)

__device__ __forceinline__ void  stf(float* p, float v) { *p = v; }
__device__ __forceinline__ void  stf(bf16* p, float v)  { *p = __float2bfloat16(v); }

__device__ __forceinline__ void gload_lds16(const bf16* g, bf16* l) {
    __builtin_amdgcn_global_load_lds(
        (const __attribute__((address_space(1))) void*)g,
        (__attribute__((address_space(3))) void*)l, 16, 0, 0);
}

#define VMCNT(n) asm volatile("s_waitcnt vmcnt(" #n ")" ::: "memory")

// ---------------------------------------------------------------------------
// One-shot prep: 7 weight transposes, bias concat, x -> bf16, RPE pos+norm.
__global__ __launch_bounds__(256) void k_prep(const float* __restrict__ Wu,
                                              const float* __restrict__ Wv,
                                              const float* __restrict__ Wo,
                                              const float* __restrict__ w1,
                                              const float* __restrict__ w2,
                                              const float* __restrict__ w3,
                                              const float* __restrict__ wOut,
                                              const float* __restrict__ bu,
                                              const float* __restrict__ bv,
                                              const float* __restrict__ x,
                                              const float* __restrict__ rpw,
                                              const float* __restrict__ rpb,
                                              bf16* __restrict__ WuvT,
                                              bf16* __restrict__ WoT,
                                              bf16* __restrict__ w1T,
                                              bf16* __restrict__ w2T,
                                              bf16* __restrict__ w3T,
                                              bf16* __restrict__ wOutT,
                                              float* __restrict__ biasUv,
                                              bf16* __restrict__ xb,
                                              bf16* __restrict__ rnA) {
    __shared__ float t[32][33];
    __shared__ float ps[4];
    const int tid = threadIdx.x;
    int b = blockIdx.x;

    const float* src = nullptr; bf16* dst = nullptr; int R = 0, C = 0, nbx = 0;
    if (b < 512)        { src = Wu;   dst = WuvT;                      R = 512;  C = 1024; nbx = 32; }
    else if (b < 1024)  { b -= 512;   src = Wv; dst = WuvT + (size_t)1024 * 512; R = 512; C = 1024; nbx = 32; }
    else if (b < 1536)  { b -= 1024;  src = Wo;   dst = WoT;           R = 1024; C = 512;  nbx = 16; }
    else if (b < 1792)  { b -= 1536;  src = w1;   dst = w1T;           R = 512;  C = 512;  nbx = 16; }
    else if (b < 2048)  { b -= 1792;  src = w2;   dst = w2T;           R = 512;  C = 512;  nbx = 16; }
    else if (b < 2304)  { b -= 2048;  src = w3;   dst = w3T;           R = 512;  C = 512;  nbx = 16; }
    else if (b < 2816)  { b -= 2304;  src = wOut; dst = wOutT;         R = 512;  C = 1024; nbx = 32; }
    else if (b < 2824) {               // bias concat
        int c = (b - 2816) * 256 + tid;
        if (c < 2048) biasUv[c] = (c < 1024) ? bu[c] : bv[c - 1024];
        return;
    } else if (b < 9096) {             // x -> bf16
        int i = (b - 2824) * 256 + tid;
        float4 v = *(const float4*)&x[(size_t)i * 4];
        bf16* d = &xb[(size_t)i * 4];
        d[0] = __float2bfloat16(v.x);
        d[1] = __float2bfloat16(v.y);
        d[2] = __float2bfloat16(v.z);
        d[3] = __float2bfloat16(v.w);
        return;
    } else {                           // RPE pos + rmsnorm + relu: 729 blocks
        int p = b - 9096;
        float ii = (float)(p / 27 - 13);
        float jj = (float)(p % 27 - 13);
        int c0 = tid, c1 = tid + 256;
        float v0 = ii * rpw[c0] + jj * rpw[512 + c0] + rpb[c0];
        float v1 = ii * rpw[c1] + jj * rpw[512 + c1] + rpb[c1];
        float s = v0 * v0 + v1 * v1;
        #pragma unroll
        for (int off = 32; off; off >>= 1) s += __shfl_down(s, off, 64);
        if ((tid & 63) == 0) ps[tid >> 6] = s;
        __syncthreads();
        float tot = ps[0] + ps[1] + ps[2] + ps[3];
        float scale = rsqrtf(tot * (1.0f / 512.0f) + RMS_EPS);
        rnA[(size_t)p * 512 + c0] = __float2bfloat16(fmaxf(v0 * scale, 0.0f));
        rnA[(size_t)p * 512 + c1] = __float2bfloat16(fmaxf(v1 * scale, 0.0f));
        return;
    }
    int bx = (b % nbx) * 32;
    int by = (b / nbx) * 32;
    int tx = tid & 31, ty = tid >> 5;
    #pragma unroll
    for (int i = 0; i < 4; ++i)
        t[ty + i * 8][tx] = src[(size_t)(by + ty + i * 8) * C + bx + tx];
    __syncthreads();
    #pragma unroll
    for (int i = 0; i < 4; ++i)
        dst[(size_t)(bx + ty + i * 8) * R + by + tx] = __float2bfloat16(t[tx][ty + i * 8]);
}

// ---------------------------------------------------------------------------
// RPE-layer GEMM body (64x64 tile, BK=32, 4 waves of a 256-lane group),
// double-buffered staging with counted vmcnt (R16-proven).
template <int SCALE_IN, int EPI>
__device__ __forceinline__ void rpe_body(const bf16* __restrict__ A,
                                         const bf16* __restrict__ Bt,
                                         const float* __restrict__ bias,
                                         const float* __restrict__ pIn,
                                         float* __restrict__ pOut,
                                         bf16* __restrict__ out,
                                         int bx, int by, int M, int N, int K,
                                         bf16* As, bf16* Bs, int tid) {
    const int m0 = by * 64;
    const int n0 = bx * 64;
    const int lane = tid & 63;
    const int w = (tid >> 6) & 3;
    const int lr = lane & 15;
    const int lk = (lane >> 4) * 8;
    const int row = tid >> 2;
    const int seg = (tid & 3) * 8;

    f32x4 acc[4] = {};
    const int KT = K >> 5;

    gload_lds16(&A[(size_t)(m0 + row) * K + seg], &As[tid * 8]);
    gload_lds16(&Bt[(size_t)(n0 + row) * K + seg], &Bs[tid * 8]);
    for (int t = 0; t < KT; ++t) {
        const int d = t & 1;
        if (t + 1 < KT) {
            gload_lds16(&A[(size_t)(m0 + row) * K + (t + 1) * 32 + seg], &As[(d ^ 1) * 2048 + tid * 8]);
            gload_lds16(&Bt[(size_t)(n0 + row) * K + (t + 1) * 32 + seg], &Bs[(d ^ 1) * 2048 + tid * 8]);
            VMCNT(2);
        } else {
            VMCNT(0);
        }
        __builtin_amdgcn_s_barrier();
        __builtin_amdgcn_sched_barrier(0);
        bf16x8 af = *(const bf16x8*)&As[d * 2048 + (w * 16 + lr) * 32 + lk];
        #pragma unroll
        for (int j = 0; j < 4; ++j) {
            bf16x8 bf = *(const bf16x8*)&Bs[d * 2048 + (j * 16 + lr) * 32 + lk];
            acc[j] = __builtin_amdgcn_mfma_f32_16x16x32_bf16(af, bf, acc[j], 0, 0, 0);
        }
        __builtin_amdgcn_s_barrier();
    }

    const int crow = (lane >> 4) * 4;
    const int ccol = lane & 15;
    float sc[4];
    #pragma unroll
    for (int r = 0; r < 4; ++r) {
        sc[r] = 1.0f;
        if (SCALE_IN) {
            int gr = m0 + w * 16 + crow + r;
            if (gr < M) {
                const float* pp = &pIn[(size_t)gr * 8];
                float s8 = pp[0] + pp[1] + pp[2] + pp[3] + pp[4] + pp[5] + pp[6] + pp[7];
                sc[r] = rsqrtf(s8 * (1.0f / 512.0f) + RMS_EPS);
            }
        }
    }
    float rowsq[4] = {0.f, 0.f, 0.f, 0.f};
    #pragma unroll
    for (int j = 0; j < 4; ++j) {
        int gc = n0 + j * 16 + ccol;
        float bb = bias[gc];
        #pragma unroll
        for (int r = 0; r < 4; ++r) {
            int gr = m0 + w * 16 + crow + r;
            float val = acc[j][r] * sc[r] + bb;
            if (EPI == 0) {
                rowsq[r] += val * val;
                if (gr < M) out[(size_t)gr * N + gc] = __float2bfloat16(fmaxf(val, 0.0f));
            } else {
                if (gr < M) {
                    int i = gr / 27, jj = gr % 27;
                    float decay = exp2f((float)(abs(i - 13) + abs(jj - 13)) * GAMMA_LOG2);
                    out[(size_t)gr * N + gc] = __float2bfloat16(val * decay);
                }
            }
        }
    }
    if (EPI == 0) {
        #pragma unroll
        for (int r = 0; r < 4; ++r) {
            #pragma unroll
            for (int m = 1; m < 16; m <<= 1) rowsq[r] += __shfl_xor(rowsq[r], m, 64);
        }
        if ((lane & 15) == 0) {
            #pragma unroll
            for (int r = 0; r < 4; ++r) {
                int gr = m0 + w * 16 + crow + r;
                if (gr < M) pOut[(size_t)gr * 8 + bx] = rowsq[r];
            }
        }
    }
}

// Standalone 256-thread wrapper (L4).
template <int SCALE_IN, int EPI>
__global__ __launch_bounds__(256) void k_rpe_gemm(const bf16* __restrict__ A,
                                                  const bf16* __restrict__ Bt,
                                                  const float* __restrict__ bias,
                                                  const float* __restrict__ pIn,
                                                  float* __restrict__ pOut,
                                                  bf16* __restrict__ out,
                                                  int M, int N, int K) {
    __shared__ bf16 As[2][2048];
    __shared__ bf16 Bs[2][2048];
    rpe_body<SCALE_IN, EPI>(A, Bt, bias, pIn, pOut, out,
                            blockIdx.x, blockIdx.y, M, N, K,
                            &As[0][0], &Bs[0][0], threadIdx.x);
}

// ---------------------------------------------------------------------------
// m97-structure 128x128 MFMA GEMM (out GEMM; multi-block/CU).
template <int EPI, typename TO>
__global__ __launch_bounds__(256) void k_mgemm(const bf16* __restrict__ A, int lda,
                                               const bf16* __restrict__ Bt,
                                               const float* __restrict__ bias,
                                               TO* __restrict__ out, int ldo,
                                               int M, int N, int K) {
    __shared__ bf16 As[128 * 32];
    __shared__ bf16 Bs[128 * 32];
    const int tid = threadIdx.x;
    const int m0 = blockIdx.y * 128;
    const int n0 = blockIdx.x * 128;
    const int lane = tid & 63;
    const int w = tid >> 6;
    const int wr = (w >> 1) * 64;
    const int wc = (w & 1) * 64;
    const int lr = lane & 15;
    const int lk = (lane >> 4) * 8;

    f32x4 acc[4][4] = {};

    for (int k0 = 0; k0 < K; k0 += 32) {
        #pragma unroll
        for (int t = 0; t < 2; ++t) {
            int flat = t * 256 + tid;
            int row = flat >> 2;
            int seg = (flat & 3) * 8;
            gload_lds16(&A[(size_t)(m0 + row) * lda + k0 + seg], &As[flat * 8]);
            gload_lds16(&Bt[(size_t)(n0 + row) * K + k0 + seg], &Bs[flat * 8]);
        }
        __syncthreads();
        bf16x8 af[4], bf[4];
        #pragma unroll
        for (int i = 0; i < 4; ++i) {
            af[i] = *(const bf16x8*)&As[(wr + i * 16 + lr) * 32 + lk];
            bf[i] = *(const bf16x8*)&Bs[(wc + i * 16 + lr) * 32 + lk];
        }
        #pragma unroll
        for (int i = 0; i < 4; ++i)
            #pragma unroll
            for (int j = 0; j < 4; ++j)
                acc[i][j] = __builtin_amdgcn_mfma_f32_16x16x32_bf16(af[i], bf[j], acc[i][j], 0, 0, 0);
        __syncthreads();
    }

    const int crow = (lane >> 4) * 4;
    const int ccol = lane & 15;
    #pragma unroll
    for (int i = 0; i < 4; ++i)
        #pragma unroll
        for (int j = 0; j < 4; ++j) {
            int gc = n0 + wc + j * 16 + ccol;
            float bb = bias[gc];
            #pragma unroll
            for (int r = 0; r < 4; ++r) {
                int gr = m0 + wr + i * 16 + crow + r;
                float val = acc[i][j][r] + bb;
                if (EPI == 1) val = val / (1.0f + expf(-val));
                stf(&out[(size_t)gr * ldo + gc], val);
            }
        }
}

// ---------------------------------------------------------------------------
// Combined dispatch: blocks [0,392) run the frozen 8-phase 256^2 uv GEMM;
// blocks [392,392+48) run RPE layer-1 (two 64x64 tiles per 512-thr block).
__global__ __launch_bounds__(512, 2) void k_uv_l1(const bf16* __restrict__ A, int lda,
                                                  const bf16* __restrict__ Bt,
                                                  const float* __restrict__ bias,
                                                  bf16* __restrict__ out, int ldo,
                                                  int nb /* N/256 */,
                                                  const bf16* __restrict__ rA,
                                                  const bf16* __restrict__ w1T,
                                                  const float* __restrict__ b1,
                                                  float* __restrict__ p1,
                                                  bf16* __restrict__ rB) {
    constexpr int KT = 8;
    constexpr int K = KT * 64;
    __shared__ __align__(16) char lds[131072];

    const int tid = threadIdx.x;

    if (blockIdx.x >= UVNWG) {
        const int orig = (blockIdx.x - UVNWG) * 2 + (tid >> 8);   // 0..95
        const int half = tid >> 8;
        bf16* As = (bf16*)(lds + half * 32768);
        bf16* Bs = (bf16*)(lds + half * 32768 + 8192);
        rpe_body<0, 0>(rA, w1T, b1, nullptr, p1, rB,
                       orig & 7, orig >> 3, RPOS, 512, 512, As, Bs, tid & 255);
        return;
    }

    const int lane = tid & 63;
    const int wid = tid >> 6;
    const int wr = wid >> 2;
    const int wc = wid & 3;

    int wgid = blockIdx.x;
    {
        int cpx = UVNWG >> 3;          // 49
        wgid = (wgid & 7) * cpx + (wgid >> 3);
    }
    const int m0 = (wgid / nb) * 256;
    const int n0 = (wgid % nb) * 256;

    auto ldsA = [&](int d, int kh) -> char* { return (char*)lds + d * 32768 + kh * 16384; };
    auto ldsB = [&](int d, int kh) -> char* { return (char*)lds + 65536 + d * 32768 + kh * 16384; };

    auto stage = [&](int op, int kh, int tt) {
        char* base = op ? ldsB(tt & 1, kh) : ldsA(tt & 1, kh);
        const bf16* g = op ? Bt : A;
        const int rowbase = op ? n0 : m0;
        const int ldr = op ? K : lda;
        #pragma unroll
        for (int l = 0; l < 2; ++l) {
            int q = tid + l * 512;
            int r = q >> 2;
            int cl = (q & 3) ^ ((r ^ (r >> 2)) & 3);
            const bf16* src = g + (size_t)(rowbase + r) * ldr + tt * 64 + kh * 32 + cl * 8;
            gload_lds16(src, (bf16*)(base + q * 16));
        }
    };
    auto rdA = [&](int d, int ks, int mi) -> bf16x8 {
        int row = wr * 128 + mi * 16 + (lane & 15);
        int ch = (lane >> 4) ^ ((row ^ (row >> 2)) & 3);
        return *(const bf16x8*)(ldsA(d, ks) + row * 64 + ch * 16);
    };
    auto rdB = [&](int d, int ks, int nj) -> bf16x8 {
        int row = wc * 64 + nj * 16 + (lane & 15);
        int ch = (lane >> 4) ^ ((row ^ (row >> 2)) & 3);
        return *(const bf16x8*)(ldsB(d, ks) + row * 64 + ch * 16);
    };

    f32x4 acc[8][4] = {};
    bf16x8 aF[4], bF[4];

    stage(0, 0, 0); stage(1, 0, 0); stage(0, 1, 0); stage(1, 1, 0);
    stage(0, 0, 1); stage(1, 0, 1);
    VMCNT(8);
    __builtin_amdgcn_s_barrier();
    __builtin_amdgcn_sched_barrier(0);

    #pragma unroll
    for (int t = 0; t < KT; ++t) {
        const int d = t & 1;
        #pragma unroll
        for (int mi = 0; mi < 4; ++mi) aF[mi] = rdA(d, 0, mi);
        #pragma unroll
        for (int nj = 0; nj < 4; ++nj) bF[nj] = rdB(d, 0, nj);
        if (t + 1 < KT) stage(0, 1, t + 1);
        __builtin_amdgcn_s_barrier();
        __builtin_amdgcn_s_setprio(1);
        #pragma unroll
        for (int mi = 0; mi < 4; ++mi)
            #pragma unroll
            for (int nj = 0; nj < 4; ++nj)
                acc[mi][nj] = __builtin_amdgcn_mfma_f32_16x16x32_bf16(aF[mi], bF[nj], acc[mi][nj], 0, 0, 0);
        __builtin_amdgcn_s_setprio(0);
        __builtin_amdgcn_s_barrier();
        #pragma unroll
        for (int mi = 0; mi < 4; ++mi) aF[mi] = rdA(d, 0, mi + 4);
        if (t + 1 < KT) stage(1, 1, t + 1);
        if (t + 1 < KT) { VMCNT(8); } else { VMCNT(0); }
        __builtin_amdgcn_s_barrier();
        __builtin_amdgcn_sched_barrier(0);
        __builtin_amdgcn_s_setprio(1);
        #pragma unroll
        for (int mi = 0; mi < 4; ++mi)
            #pragma unroll
            for (int nj = 0; nj < 4; ++nj)
                acc[mi + 4][nj] = __builtin_amdgcn_mfma_f32_16x16x32_bf16(aF[mi], bF[nj], acc[mi + 4][nj], 0, 0, 0);
        __builtin_amdgcn_s_setprio(0);
        __builtin_amdgcn_s_barrier();
        #pragma unroll
        for (int mi = 0; mi < 4; ++mi) aF[mi] = rdA(d, 1, mi);
        #pragma unroll
        for (int nj = 0; nj < 4; ++nj) bF[nj] = rdB(d, 1, nj);
        if (t + 2 < KT) stage(0, 0, t + 2);
        __builtin_amdgcn_s_barrier();
        __builtin_amdgcn_s_setprio(1);
        #pragma unroll
        for (int mi = 0; mi < 4; ++mi)
            #pragma unroll
            for (int nj = 0; nj < 4; ++nj)
                acc[mi][nj] = __builtin_amdgcn_mfma_f32_16x16x32_bf16(aF[mi], bF[nj], acc[mi][nj], 0, 0, 0);
        __builtin_amdgcn_s_setprio(0);
        __builtin_amdgcn_s_barrier();
        #pragma unroll
        for (int mi = 0; mi < 4; ++mi) aF[mi] = rdA(d, 1, mi + 4);
        if (t + 2 < KT) stage(1, 0, t + 2);
        if (t + 2 < KT)      { VMCNT(8); }
        else if (t + 1 < KT) { VMCNT(4); }
        __builtin_amdgcn_s_barrier();
        __builtin_amdgcn_sched_barrier(0);
        __builtin_amdgcn_s_setprio(1);
        #pragma unroll
        for (int mi = 0; mi < 4; ++mi)
            #pragma unroll
            for (int nj = 0; nj < 4; ++nj)
                acc[mi + 4][nj] = __builtin_amdgcn_mfma_f32_16x16x32_bf16(aF[mi], bF[nj], acc[mi + 4][nj], 0, 0, 0);
        __builtin_amdgcn_s_setprio(0);
        __builtin_amdgcn_s_barrier();
    }

    const int crow = (lane >> 4) * 4;
    const int ccol = lane & 15;
    #pragma unroll
    for (int mi = 0; mi < 8; ++mi)
        #pragma unroll
        for (int nj = 0; nj < 4; ++nj) {
            int gc = n0 + wc * 64 + nj * 16 + ccol;
            float bb = bias[gc];
            #pragma unroll
            for (int r = 0; r < 4; ++r) {
                int gr = m0 + wr * 128 + mi * 16 + crow + r;
                float val = acc[mi][nj][r] + bb;
                val = val / (1.0f + expf(-val));
                stf(&out[(size_t)gr * ldo + gc], val);
            }
        }
}

// ---------------------------------------------------------------------------
// Combined dispatch: blocks [0,512) transpose half the batches
// (b = bbase + idx>>4) into Vt; blocks [512,512+96) run one RPE layer.
__global__ __launch_bounds__(256) void k_vt_rpe(const bf16* __restrict__ uv,
                                                bf16* __restrict__ Vt, int bbase,
                                                const bf16* __restrict__ rIn,
                                                const bf16* __restrict__ wT,
                                                const float* __restrict__ bias,
                                                const float* __restrict__ pIn,
                                                float* __restrict__ pOut,
                                                bf16* __restrict__ rOut) {
    __shared__ __align__(16) char lraw[25872];
    const int tid = threadIdx.x;

    if (blockIdx.x >= 512) {
        const int orig = blockIdx.x - 512;      // 0..95
        bf16* As = (bf16*)lraw;
        bf16* Bs = (bf16*)(lraw + 8192);
        rpe_body<1, 0>(rIn, wT, bias, pIn, pOut, rOut,
                       orig & 7, orig >> 3, RPOS, 512, 512, As, Bs, tid);
        return;
    }

    typedef bf16 row66[66];
    row66* t = (row66*)lraw;
    const int c0 = (blockIdx.x & 15) * 64;
    const int b  = bbase + (blockIdx.x >> 4);
    for (int f = tid; f < 196 * 64; f += 256) {
        int ij = f >> 6, cl = f & 63;
        t[ij][cl] = uv[((size_t)b * 196 + ij) * 2048 + 1024 + c0 + cl];
    }
    __syncthreads();
    const bf16 z = __float2bfloat16(0.0f);
    for (int f = tid; f < 64 * 224; f += 256) {
        int cl = f / 224, ij = f - cl * 224;
        Vt[((size_t)(c0 + cl) * 64 + b) * 224 + ij] = (ij < 196) ? t[ij][cl] : z;
    }
}

// ---------------------------------------------------------------------------
// Per-channel Toeplitz GEMM; both mh halves in one block (Vc/As read once).
__global__ __launch_bounds__(256) void k_convm(const bf16* __restrict__ Ab,
                                               const bf16* __restrict__ Vt,
                                               bf16* __restrict__ Yt) {
    __shared__ __align__(16) bf16 Ts[112 * 232];
    __shared__ bf16 As[736];
    const int cl = blockIdx.x;
    const int c = (int)blockIdx.y * 512 + cl;
    const int tid = threadIdx.x;

    for (int e = tid; e < 729; e += 256)
        As[e] = Ab[(size_t)e * 1024 + c];

    const int lane = tid & 63;
    const int w = tid >> 6;
    const int lr = lane & 15;
    const int lk = (lane >> 4) * 8;
    const bf16* Vc = Vt + (size_t)c * 64 * 224;

    bf16x8 bfr[7];
    #pragma unroll
    for (int ks = 0; ks < 7; ++ks)
        bfr[ks] = *(const bf16x8*)&Vc[(size_t)(w * 16 + lr) * 224 + ks * 32 + lk];

    __syncthreads();   // As ready

    const bf16 z = __float2bfloat16(0.0f);
    const int crow = (lane >> 4) * 4;
    const int bb = w * 16 + (lane & 15);

    #pragma unroll
    for (int mh = 0; mh < 2; ++mh) {
        const int mbase = mh * 112;
        if (tid < 224) {
            const int i = tid / 14, j = tid - i * 14;
            const bool kvalid = tid < 196;
            int p = mbase / 14, q = 0;
            for (int r = 0; r < 112; ++r) {
                bf16 val = z;
                if (kvalid && (mbase + r) < 196)
                    val = As[(p - i + 13) * 27 + (q - j + 13)];
                Ts[r * 232 + tid] = val;
                if (++q == 14) { q = 0; ++p; }
            }
        }
        __syncthreads();   // Ts ready

        f32x4 acc[7] = {};
        #pragma unroll
        for (int ks = 0; ks < 7; ++ks)
            #pragma unroll
            for (int mi = 0; mi < 7; ++mi) {
                bf16x8 a = *(const bf16x8*)&Ts[(mi * 16 + lr) * 232 + ks * 32 + lk];
                acc[mi] = __builtin_amdgcn_mfma_f32_16x16x32_bf16(a, bfr[ks], acc[mi], 0, 0, 0);
            }

        #pragma unroll
        for (int mi = 0; mi < 7; ++mi) {
            int pq = mbase + mi * 16 + crow;
            #pragma unroll
            for (int r = 0; r < 4; ++r)
                if (pq + r < 196)
                    Yt[((size_t)c * 196 + pq + r) * 64 + bb] = __float2bfloat16(acc[mi][r]);
        }
        __syncthreads();   // Ts reads done before next build
    }
}

// ---------------------------------------------------------------------------
__global__ __launch_bounds__(256) void k_gate(bf16* __restrict__ uv,
                                              const bf16* __restrict__ Yt) {
    const int pq = blockIdx.x;
    const int ct = blockIdx.y;
    const int cb = (int)blockIdx.z * 512;
    const int tid = threadIdx.x;
    __shared__ float t[64][65];
    for (int f = tid; f < 64 * 64; f += 256) {
        int cr = f >> 6, bcol = f & 63;
        t[cr][bcol] = __bfloat162float(Yt[((size_t)(cb + ct * 64 + cr) * 196 + pq) * 64 + bcol]);
    }
    __syncthreads();
    for (int f = tid; f < 64 * 64; f += 256) {
        int br = f >> 6, cc = f & 63;
        size_t row = (size_t)br * 196 + pq;
        int cglob = cb + ct * 64 + cc;
        float uu = __bfloat162float(uv[row * 2048 + cglob]);
        uv[row * 2048 + 1024 + cglob] = __float2bfloat16(t[cc][br] * uu);
    }
}

// ---------------------------------------------------------------------------
extern "C" void kernel_launch(void* const* d_in, const int* in_sizes, int n_in,
                              void* d_out, int out_size, void* d_ws, size_t ws_size,
                              hipStream_t stream) {
    const float* x    = (const float*)d_in[0];
    const float* Wu   = (const float*)d_in[3];
    const float* bu   = (const float*)d_in[4];
    const float* Wv   = (const float*)d_in[5];
    const float* bv   = (const float*)d_in[6];
    const float* Wo   = (const float*)d_in[7];
    const float* bo   = (const float*)d_in[8];
    const float* rpw  = (const float*)d_in[9];
    const float* rpb  = (const float*)d_in[10];
    const float* w1   = (const float*)d_in[11];
    const float* b1   = (const float*)d_in[12];
    const float* w2   = (const float*)d_in[13];
    const float* b2   = (const float*)d_in[14];
    const float* w3   = (const float*)d_in[15];
    const float* b3   = (const float*)d_in[16];
    const float* wOut = (const float*)d_in[17];
    const float* bOut = (const float*)d_in[18];

    char* ws = (char*)d_ws;
    size_t off = 0;
    auto take = [&](size_t bytes) { char* p = ws + off; off += (bytes + 255) & ~size_t(255); return p; };
    bf16*  rnA    = (bf16*)take((size_t)768 * 512 * 2);
    bf16*  rnB    = (bf16*)take((size_t)768 * 512 * 2);
    float* p1     = (float*)take((size_t)768 * 8 * 4);
    float* p2     = (float*)take((size_t)768 * 8 * 4);
    float* p3     = (float*)take((size_t)768 * 8 * 4);
    bf16*  Ab     = (bf16*)take((size_t)RPOS * 1024 * 2);
    bf16*  xb     = (bf16*)take((size_t)ROWS * EE * 2);
    bf16*  WuvT   = (bf16*)take((size_t)2048 * 512 * 2);
    bf16*  WoT    = (bf16*)take((size_t)512 * 1024 * 2);
    bf16*  w1T    = (bf16*)take((size_t)512 * 512 * 2);
    bf16*  w2T    = (bf16*)take((size_t)512 * 512 * 2);
    bf16*  w3T    = (bf16*)take((size_t)512 * 512 * 2);
    bf16*  wOutT  = (bf16*)take((size_t)1024 * 512 * 2);
    float* biasUv = (float*)take(2048 * 4);
    bf16*  uvb    = (bf16*)take((size_t)ROWS * 2048 * 2);
    bf16*  Vt     = (bf16*)take((size_t)1024 * 64 * 224 * 2);
    bf16*  Yt     = (bf16*)take((size_t)1024 * 196 * 64 * 2);

    // --- all prep (incl. RPE pos+norm) ---
    k_prep<<<9825, 256, 0, stream>>>(Wu, Wv, Wo, w1, w2, w3, wOut, bu, bv, x,
                                     rpw, rpb,
                                     WuvT, WoT, w1T, w2T, w3T, wOutT, biasUv, xb, rnA);

    // --- uv GEMM + RPE L1 co-dispatched (440 blocks) ---
    k_uv_l1<<<UVNWG + 48, 512, 0, stream>>>(xb, 512, WuvT, biasUv, uvb, 2048, 8,
                                            rnA, w1T, b1, p1, rnB);

    // --- v transpose (b 0..31) + RPE L2; then (b 32..63) + RPE L3 ---
    k_vt_rpe<<<608, 256, 0, stream>>>(uvb, Vt, 0,  rnB, w2T, b2, p1, p2, rnA);
    k_vt_rpe<<<608, 256, 0, stream>>>(uvb, Vt, 32, rnA, w3T, b3, p2, p3, rnB);

    // --- RPE L4 (Toeplitz coeffs) ---
    k_rpe_gemm<1, 2><<<dim3(16, 12), 256, 0, stream>>>(rnB, wOutT, bOut, p3, nullptr, Ab, RPOS, 1024, 512);

    // --- Toeplitz conv (MFMA), both mh halves per block ---
    k_convm<<<dim3(512, 2), 256, 0, stream>>>(Ab, Vt, Yt);

    // --- gating ---
    k_gate<<<dim3(196, 8, 2), 256, 0, stream>>>(uvb, Yt);

    // --- out = g @ Wo + bo  (m97 128^2, grid 392) ---
    k_mgemm<0, float><<<dim3(4, 98), 256, 0, stream>>>(uvb + 1024, 2048, WoT, bo,
                                                       (float*)d_out, 512, ROWS, 512, 1024);
}

// Round 19
// 191.398 us; speedup vs baseline: 1.1372x; 1.0033x over previous
//
#include <hip/hip_runtime.h>
#include <hip/hip_bf16.h>

typedef __hip_bfloat16 bf16;
typedef __attribute__((ext_vector_type(8))) short bf16x8;
typedef __attribute__((ext_vector_type(4))) float f32x4;

constexpr int NB    = 64;
constexpr int EE    = 512;
constexpr int RPOS  = 27 * 27;       // 729
constexpr int ROWS  = NB * 14 * 14;  // 12544
constexpr int UVNWG = 392;           // uv GEMM tiles (49 x 8)

#define RMS_EPS 1e-6f
#define GAMMA_LOG2 (-0.00144344319f)   // log2(0.999)

__device__ __forceinline__ void  stf(float* p, float v) { *p = v; }
__device__ __forceinline__ void  stf(bf16* p, float v)  { *p = __float2bfloat16(v); }

__device__ __forceinline__ void gload_lds16(const bf16* g, bf16* l) {
    __builtin_amdgcn_global_load_lds(
        (const __attribute__((address_space(1))) void*)g,
        (__attribute__((address_space(3))) void*)l, 16, 0, 0);
}

#define VMCNT(n) asm volatile("s_waitcnt vmcnt(" #n ")" ::: "memory")

// ---------------------------------------------------------------------------
// One-shot prep: 7 weight transposes, bias concat, x -> bf16, RPE pos+norm.
__global__ __launch_bounds__(256) void k_prep(const float* __restrict__ Wu,
                                              const float* __restrict__ Wv,
                                              const float* __restrict__ Wo,
                                              const float* __restrict__ w1,
                                              const float* __restrict__ w2,
                                              const float* __restrict__ w3,
                                              const float* __restrict__ wOut,
                                              const float* __restrict__ bu,
                                              const float* __restrict__ bv,
                                              const float* __restrict__ x,
                                              const float* __restrict__ rpw,
                                              const float* __restrict__ rpb,
                                              bf16* __restrict__ WuvT,
                                              bf16* __restrict__ WoT,
                                              bf16* __restrict__ w1T,
                                              bf16* __restrict__ w2T,
                                              bf16* __restrict__ w3T,
                                              bf16* __restrict__ wOutT,
                                              float* __restrict__ biasUv,
                                              bf16* __restrict__ xb,
                                              bf16* __restrict__ rnA) {
    __shared__ float t[32][33];
    __shared__ float ps[4];
    const int tid = threadIdx.x;
    int b = blockIdx.x;

    const float* src = nullptr; bf16* dst = nullptr; int R = 0, C = 0, nbx = 0;
    if (b < 512)        { src = Wu;   dst = WuvT;                      R = 512;  C = 1024; nbx = 32; }
    else if (b < 1024)  { b -= 512;   src = Wv; dst = WuvT + (size_t)1024 * 512; R = 512; C = 1024; nbx = 32; }
    else if (b < 1536)  { b -= 1024;  src = Wo;   dst = WoT;           R = 1024; C = 512;  nbx = 16; }
    else if (b < 1792)  { b -= 1536;  src = w1;   dst = w1T;           R = 512;  C = 512;  nbx = 16; }
    else if (b < 2048)  { b -= 1792;  src = w2;   dst = w2T;           R = 512;  C = 512;  nbx = 16; }
    else if (b < 2304)  { b -= 2048;  src = w3;   dst = w3T;           R = 512;  C = 512;  nbx = 16; }
    else if (b < 2816)  { b -= 2304;  src = wOut; dst = wOutT;         R = 512;  C = 1024; nbx = 32; }
    else if (b < 2824) {               // bias concat
        int c = (b - 2816) * 256 + tid;
        if (c < 2048) biasUv[c] = (c < 1024) ? bu[c] : bv[c - 1024];
        return;
    } else if (b < 9096) {             // x -> bf16
        int i = (b - 2824) * 256 + tid;
        float4 v = *(const float4*)&x[(size_t)i * 4];
        bf16* d = &xb[(size_t)i * 4];
        d[0] = __float2bfloat16(v.x);
        d[1] = __float2bfloat16(v.y);
        d[2] = __float2bfloat16(v.z);
        d[3] = __float2bfloat16(v.w);
        return;
    } else {                           // RPE pos + rmsnorm + relu: 729 blocks
        int p = b - 9096;
        float ii = (float)(p / 27 - 13);
        float jj = (float)(p % 27 - 13);
        int c0 = tid, c1 = tid + 256;
        float v0 = ii * rpw[c0] + jj * rpw[512 + c0] + rpb[c0];
        float v1 = ii * rpw[c1] + jj * rpw[512 + c1] + rpb[c1];
        float s = v0 * v0 + v1 * v1;
        #pragma unroll
        for (int off = 32; off; off >>= 1) s += __shfl_down(s, off, 64);
        if ((tid & 63) == 0) ps[tid >> 6] = s;
        __syncthreads();
        float tot = ps[0] + ps[1] + ps[2] + ps[3];
        float scale = rsqrtf(tot * (1.0f / 512.0f) + RMS_EPS);
        rnA[(size_t)p * 512 + c0] = __float2bfloat16(fmaxf(v0 * scale, 0.0f));
        rnA[(size_t)p * 512 + c1] = __float2bfloat16(fmaxf(v1 * scale, 0.0f));
        return;
    }
    int bx = (b % nbx) * 32;
    int by = (b / nbx) * 32;
    int tx = tid & 31, ty = tid >> 5;
    #pragma unroll
    for (int i = 0; i < 4; ++i)
        t[ty + i * 8][tx] = src[(size_t)(by + ty + i * 8) * C + bx + tx];
    __syncthreads();
    #pragma unroll
    for (int i = 0; i < 4; ++i)
        dst[(size_t)(bx + ty + i * 8) * R + by + tx] = __float2bfloat16(t[tx][ty + i * 8]);
}

// ---------------------------------------------------------------------------
// RPE-layer GEMM body (64x64 tile, BK=32, 4 waves of a 256-lane group),
// double-buffered, counted vmcnt, hoisted stage base pointers.
template <int SCALE_IN, int EPI>
__device__ __forceinline__ void rpe_body(const bf16* __restrict__ A,
                                         const bf16* __restrict__ Bt,
                                         const float* __restrict__ bias,
                                         const float* __restrict__ pIn,
                                         float* __restrict__ pOut,
                                         bf16* __restrict__ out,
                                         int bx, int by, int M, int N, int K,
                                         bf16* As, bf16* Bs, int tid) {
    const int m0 = by * 64;
    const int n0 = bx * 64;
    const int lane = tid & 63;
    const int w = (tid >> 6) & 3;
    const int lr = lane & 15;
    const int lk = (lane >> 4) * 8;
    const int row = tid >> 2;
    const int seg = (tid & 3) * 8;

    const bf16* pA = A + (size_t)(m0 + row) * K + seg;     // hoisted bases
    const bf16* pB = Bt + (size_t)(n0 + row) * K + seg;

    f32x4 acc[4] = {};
    const int KT = K >> 5;

    gload_lds16(pA, &As[tid * 8]);
    gload_lds16(pB, &Bs[tid * 8]);
    for (int t = 0; t < KT; ++t) {
        const int d = t & 1;
        if (t + 1 < KT) {
            gload_lds16(pA + (t + 1) * 32, &As[(d ^ 1) * 2048 + tid * 8]);
            gload_lds16(pB + (t + 1) * 32, &Bs[(d ^ 1) * 2048 + tid * 8]);
            VMCNT(2);
        } else {
            VMCNT(0);
        }
        __builtin_amdgcn_s_barrier();
        __builtin_amdgcn_sched_barrier(0);
        bf16x8 af = *(const bf16x8*)&As[d * 2048 + (w * 16 + lr) * 32 + lk];
        #pragma unroll
        for (int j = 0; j < 4; ++j) {
            bf16x8 bf = *(const bf16x8*)&Bs[d * 2048 + (j * 16 + lr) * 32 + lk];
            acc[j] = __builtin_amdgcn_mfma_f32_16x16x32_bf16(af, bf, acc[j], 0, 0, 0);
        }
        __builtin_amdgcn_s_barrier();
    }

    const int crow = (lane >> 4) * 4;
    const int ccol = lane & 15;
    float sc[4];
    #pragma unroll
    for (int r = 0; r < 4; ++r) {
        sc[r] = 1.0f;
        if (SCALE_IN) {
            int gr = m0 + w * 16 + crow + r;
            if (gr < M) {
                const float* pp = &pIn[(size_t)gr * 8];
                float s8 = pp[0] + pp[1] + pp[2] + pp[3] + pp[4] + pp[5] + pp[6] + pp[7];
                sc[r] = rsqrtf(s8 * (1.0f / 512.0f) + RMS_EPS);
            }
        }
    }
    float rowsq[4] = {0.f, 0.f, 0.f, 0.f};
    #pragma unroll
    for (int j = 0; j < 4; ++j) {
        int gc = n0 + j * 16 + ccol;
        float bb = bias[gc];
        #pragma unroll
        for (int r = 0; r < 4; ++r) {
            int gr = m0 + w * 16 + crow + r;
            float val = acc[j][r] * sc[r] + bb;
            if (EPI == 0) {
                rowsq[r] += val * val;
                if (gr < M) out[(size_t)gr * N + gc] = __float2bfloat16(fmaxf(val, 0.0f));
            } else {
                if (gr < M) {
                    int i = gr / 27, jj = gr % 27;
                    float decay = exp2f((float)(abs(i - 13) + abs(jj - 13)) * GAMMA_LOG2);
                    out[(size_t)gr * N + gc] = __float2bfloat16(val * decay);
                }
            }
        }
    }
    if (EPI == 0) {
        #pragma unroll
        for (int r = 0; r < 4; ++r) {
            #pragma unroll
            for (int m = 1; m < 16; m <<= 1) rowsq[r] += __shfl_xor(rowsq[r], m, 64);
        }
        if ((lane & 15) == 0) {
            #pragma unroll
            for (int r = 0; r < 4; ++r) {
                int gr = m0 + w * 16 + crow + r;
                if (gr < M) pOut[(size_t)gr * 8 + bx] = rowsq[r];
            }
        }
    }
}

// Standalone 256-thread wrapper (L4).
template <int SCALE_IN, int EPI>
__global__ __launch_bounds__(256) void k_rpe_gemm(const bf16* __restrict__ A,
                                                  const bf16* __restrict__ Bt,
                                                  const float* __restrict__ bias,
                                                  const float* __restrict__ pIn,
                                                  float* __restrict__ pOut,
                                                  bf16* __restrict__ out,
                                                  int M, int N, int K) {
    __shared__ bf16 As[2][2048];
    __shared__ bf16 Bs[2][2048];
    rpe_body<SCALE_IN, EPI>(A, Bt, bias, pIn, pOut, out,
                            blockIdx.x, blockIdx.y, M, N, K,
                            &As[0][0], &Bs[0][0], threadIdx.x);
}

// ---------------------------------------------------------------------------
// m97-structure 128x128 MFMA GEMM (out GEMM), hoisted stage bases.
template <int EPI, typename TO>
__global__ __launch_bounds__(256) void k_mgemm(const bf16* __restrict__ A, int lda,
                                               const bf16* __restrict__ Bt,
                                               const float* __restrict__ bias,
                                               TO* __restrict__ out, int ldo,
                                               int M, int N, int K) {
    __shared__ bf16 As[128 * 32];
    __shared__ bf16 Bs[128 * 32];
    const int tid = threadIdx.x;
    const int m0 = blockIdx.y * 128;
    const int n0 = blockIdx.x * 128;
    const int lane = tid & 63;
    const int w = tid >> 6;
    const int wr = (w >> 1) * 64;
    const int wc = (w & 1) * 64;
    const int lr = lane & 15;
    const int lk = (lane >> 4) * 8;

    const int rw = tid >> 2;
    const int sg = (tid & 3) * 8;
    const bf16* pA0 = A + (size_t)(m0 + rw) * lda + sg;    // hoisted bases
    const bf16* pA1 = pA0 + (size_t)64 * lda;              // flat=tid+256 -> row+64
    const bf16* pB0 = Bt + (size_t)(n0 + rw) * K + sg;
    const bf16* pB1 = pB0 + (size_t)64 * K;

    f32x4 acc[4][4] = {};

    for (int k0 = 0; k0 < K; k0 += 32) {
        gload_lds16(pA0 + k0, &As[tid * 8]);
        gload_lds16(pB0 + k0, &Bs[tid * 8]);
        gload_lds16(pA1 + k0, &As[(tid + 256) * 8]);
        gload_lds16(pB1 + k0, &Bs[(tid + 256) * 8]);
        __syncthreads();
        bf16x8 af[4], bf[4];
        #pragma unroll
        for (int i = 0; i < 4; ++i) {
            af[i] = *(const bf16x8*)&As[(wr + i * 16 + lr) * 32 + lk];
            bf[i] = *(const bf16x8*)&Bs[(wc + i * 16 + lr) * 32 + lk];
        }
        #pragma unroll
        for (int i = 0; i < 4; ++i)
            #pragma unroll
            for (int j = 0; j < 4; ++j)
                acc[i][j] = __builtin_amdgcn_mfma_f32_16x16x32_bf16(af[i], bf[j], acc[i][j], 0, 0, 0);
        __syncthreads();
    }

    const int crow = (lane >> 4) * 4;
    const int ccol = lane & 15;
    #pragma unroll
    for (int i = 0; i < 4; ++i)
        #pragma unroll
        for (int j = 0; j < 4; ++j) {
            int gc = n0 + wc + j * 16 + ccol;
            float bb = bias[gc];
            #pragma unroll
            for (int r = 0; r < 4; ++r) {
                int gr = m0 + wr + i * 16 + crow + r;
                float val = acc[i][j][r] + bb;
                if (EPI == 1) val = val / (1.0f + expf(-val));
                stf(&out[(size_t)gr * ldo + gc], val);
            }
        }
}

// ---------------------------------------------------------------------------
// Combined dispatch: blocks [0,392) run the frozen 8-phase 256^2 uv GEMM
// (stage bases hoisted; schedule unchanged); blocks [392,440) run RPE L1.
__global__ __launch_bounds__(512, 2) void k_uv_l1(const bf16* __restrict__ A, int lda,
                                                  const bf16* __restrict__ Bt,
                                                  const float* __restrict__ bias,
                                                  bf16* __restrict__ out, int ldo,
                                                  int nb /* N/256 */,
                                                  const bf16* __restrict__ rA,
                                                  const bf16* __restrict__ w1T,
                                                  const float* __restrict__ b1,
                                                  float* __restrict__ p1,
                                                  bf16* __restrict__ rB) {
    constexpr int KT = 8;
    constexpr int K = KT * 64;
    __shared__ __align__(16) char lds[131072];

    const int tid = threadIdx.x;

    if (blockIdx.x >= UVNWG) {
        const int orig = (blockIdx.x - UVNWG) * 2 + (tid >> 8);   // 0..95
        const int half = tid >> 8;
        bf16* As = (bf16*)(lds + half * 32768);
        bf16* Bs = (bf16*)(lds + half * 32768 + 8192);
        rpe_body<0, 0>(rA, w1T, b1, nullptr, p1, rB,
                       orig & 7, orig >> 3, RPOS, 512, 512, As, Bs, tid & 255);
        return;
    }

    const int lane = tid & 63;
    const int wid = tid >> 6;
    const int wr = wid >> 2;
    const int wc = wid & 3;

    int wgid = blockIdx.x;
    {
        int cpx = UVNWG >> 3;          // 49
        wgid = (wgid & 7) * cpx + (wgid >> 3);
    }
    const int m0 = (wgid / nb) * 256;
    const int n0 = (wgid % nb) * 256;

    auto ldsA = [&](int d, int kh) -> char* { return (char*)lds + d * 32768 + kh * 16384; };
    auto ldsB = [&](int d, int kh) -> char* { return (char*)lds + 65536 + d * 32768 + kh * 16384; };

    // Hoisted per-thread global bases (chunk0: q=tid, chunk1: q=tid+512).
    const bf16 *sA0, *sA1, *sB0, *sB1;
    {
        int q0 = tid, r0 = q0 >> 2, c0 = (q0 & 3) ^ ((r0 ^ (r0 >> 2)) & 3);
        int q1 = tid + 512, r1 = q1 >> 2, c1 = (q1 & 3) ^ ((r1 ^ (r1 >> 2)) & 3);
        sA0 = A + (size_t)(m0 + r0) * lda + c0 * 8;
        sA1 = A + (size_t)(m0 + r1) * lda + c1 * 8;
        sB0 = Bt + (size_t)(n0 + r0) * K + c0 * 8;
        sB1 = Bt + (size_t)(n0 + r1) * K + c1 * 8;
    }
    auto stage = [&](int op, int kh, int tt) {
        char* base = op ? ldsB(tt & 1, kh) : ldsA(tt & 1, kh);
        const int off = tt * 64 + kh * 32;
        if (op) {
            gload_lds16(sB0 + off, (bf16*)(base + tid * 16));
            gload_lds16(sB1 + off, (bf16*)(base + (tid + 512) * 16));
        } else {
            gload_lds16(sA0 + off, (bf16*)(base + tid * 16));
            gload_lds16(sA1 + off, (bf16*)(base + (tid + 512) * 16));
        }
    };
    auto rdA = [&](int d, int ks, int mi) -> bf16x8 {
        int row = wr * 128 + mi * 16 + (lane & 15);
        int ch = (lane >> 4) ^ ((row ^ (row >> 2)) & 3);
        return *(const bf16x8*)(ldsA(d, ks) + row * 64 + ch * 16);
    };
    auto rdB = [&](int d, int ks, int nj) -> bf16x8 {
        int row = wc * 64 + nj * 16 + (lane & 15);
        int ch = (lane >> 4) ^ ((row ^ (row >> 2)) & 3);
        return *(const bf16x8*)(ldsB(d, ks) + row * 64 + ch * 16);
    };

    f32x4 acc[8][4] = {};
    bf16x8 aF[4], bF[4];

    stage(0, 0, 0); stage(1, 0, 0); stage(0, 1, 0); stage(1, 1, 0);
    stage(0, 0, 1); stage(1, 0, 1);
    VMCNT(8);
    __builtin_amdgcn_s_barrier();
    __builtin_amdgcn_sched_barrier(0);

    #pragma unroll
    for (int t = 0; t < KT; ++t) {
        const int d = t & 1;
        #pragma unroll
        for (int mi = 0; mi < 4; ++mi) aF[mi] = rdA(d, 0, mi);
        #pragma unroll
        for (int nj = 0; nj < 4; ++nj) bF[nj] = rdB(d, 0, nj);
        if (t + 1 < KT) stage(0, 1, t + 1);
        __builtin_amdgcn_s_barrier();
        __builtin_amdgcn_s_setprio(1);
        #pragma unroll
        for (int mi = 0; mi < 4; ++mi)
            #pragma unroll
            for (int nj = 0; nj < 4; ++nj)
                acc[mi][nj] = __builtin_amdgcn_mfma_f32_16x16x32_bf16(aF[mi], bF[nj], acc[mi][nj], 0, 0, 0);
        __builtin_amdgcn_s_setprio(0);
        __builtin_amdgcn_s_barrier();
        #pragma unroll
        for (int mi = 0; mi < 4; ++mi) aF[mi] = rdA(d, 0, mi + 4);
        if (t + 1 < KT) stage(1, 1, t + 1);
        if (t + 1 < KT) { VMCNT(8); } else { VMCNT(0); }
        __builtin_amdgcn_s_barrier();
        __builtin_amdgcn_sched_barrier(0);
        __builtin_amdgcn_s_setprio(1);
        #pragma unroll
        for (int mi = 0; mi < 4; ++mi)
            #pragma unroll
            for (int nj = 0; nj < 4; ++nj)
                acc[mi + 4][nj] = __builtin_amdgcn_mfma_f32_16x16x32_bf16(aF[mi], bF[nj], acc[mi + 4][nj], 0, 0, 0);
        __builtin_amdgcn_s_setprio(0);
        __builtin_amdgcn_s_barrier();
        #pragma unroll
        for (int mi = 0; mi < 4; ++mi) aF[mi] = rdA(d, 1, mi);
        #pragma unroll
        for (int nj = 0; nj < 4; ++nj) bF[nj] = rdB(d, 1, nj);
        if (t + 2 < KT) stage(0, 0, t + 2);
        __builtin_amdgcn_s_barrier();
        __builtin_amdgcn_s_setprio(1);
        #pragma unroll
        for (int mi = 0; mi < 4; ++mi)
            #pragma unroll
            for (int nj = 0; nj < 4; ++nj)
                acc[mi][nj] = __builtin_amdgcn_mfma_f32_16x16x32_bf16(aF[mi], bF[nj], acc[mi][nj], 0, 0, 0);
        __builtin_amdgcn_s_setprio(0);
        __builtin_amdgcn_s_barrier();
        #pragma unroll
        for (int mi = 0; mi < 4; ++mi) aF[mi] = rdA(d, 1, mi + 4);
        if (t + 2 < KT) stage(1, 0, t + 2);
        if (t + 2 < KT)      { VMCNT(8); }
        else if (t + 1 < KT) { VMCNT(4); }
        __builtin_amdgcn_s_barrier();
        __builtin_amdgcn_sched_barrier(0);
        __builtin_amdgcn_s_setprio(1);
        #pragma unroll
        for (int mi = 0; mi < 4; ++mi)
            #pragma unroll
            for (int nj = 0; nj < 4; ++nj)
                acc[mi + 4][nj] = __builtin_amdgcn_mfma_f32_16x16x32_bf16(aF[mi], bF[nj], acc[mi + 4][nj], 0, 0, 0);
        __builtin_amdgcn_s_setprio(0);
        __builtin_amdgcn_s_barrier();
    }

    const int crow = (lane >> 4) * 4;
    const int ccol = lane & 15;
    #pragma unroll
    for (int mi = 0; mi < 8; ++mi)
        #pragma unroll
        for (int nj = 0; nj < 4; ++nj) {
            int gc = n0 + wc * 64 + nj * 16 + ccol;
            float bb = bias[gc];
            #pragma unroll
            for (int r = 0; r < 4; ++r) {
                int gr = m0 + wr * 128 + mi * 16 + crow + r;
                float val = acc[mi][nj][r] + bb;
                val = val / (1.0f + expf(-val));
                stf(&out[(size_t)gr * ldo + gc], val);
            }
        }
}

// ---------------------------------------------------------------------------
// Combined dispatch: blocks [0,512) transpose half the batches into Vt;
// blocks [512,512+96) run one RPE layer.
__global__ __launch_bounds__(256) void k_vt_rpe(const bf16* __restrict__ uv,
                                                bf16* __restrict__ Vt, int bbase,
                                                const bf16* __restrict__ rIn,
                                                const bf16* __restrict__ wT,
                                                const float* __restrict__ bias,
                                                const float* __restrict__ pIn,
                                                float* __restrict__ pOut,
                                                bf16* __restrict__ rOut) {
    __shared__ __align__(16) char lraw[25872];
    const int tid = threadIdx.x;

    if (blockIdx.x >= 512) {
        const int orig = blockIdx.x - 512;      // 0..95
        bf16* As = (bf16*)lraw;
        bf16* Bs = (bf16*)(lraw + 8192);
        rpe_body<1, 0>(rIn, wT, bias, pIn, pOut, rOut,
                       orig & 7, orig >> 3, RPOS, 512, 512, As, Bs, tid);
        return;
    }

    typedef bf16 row66[66];
    row66* t = (row66*)lraw;
    const int c0 = (blockIdx.x & 15) * 64;
    const int b  = bbase + (blockIdx.x >> 4);
    for (int f = tid; f < 196 * 64; f += 256) {
        int ij = f >> 6, cl = f & 63;
        t[ij][cl] = uv[((size_t)b * 196 + ij) * 2048 + 1024 + c0 + cl];
    }
    __syncthreads();
    const bf16 z = __float2bfloat16(0.0f);
    for (int f = tid; f < 64 * 224; f += 256) {
        int cl = f / 224, ij = f - cl * 224;
        Vt[((size_t)(c0 + cl) * 64 + b) * 224 + ij] = (ij < 196) ? t[ij][cl] : z;
    }
}

// ---------------------------------------------------------------------------
// Per-channel Toeplitz GEMM; both mh halves in one block (Vc/As read once).
__global__ __launch_bounds__(256) void k_convm(const bf16* __restrict__ Ab,
                                               const bf16* __restrict__ Vt,
                                               bf16* __restrict__ Yt) {
    __shared__ __align__(16) bf16 Ts[112 * 232];
    __shared__ bf16 As[736];
    const int cl = blockIdx.x;
    const int c = (int)blockIdx.y * 512 + cl;
    const int tid = threadIdx.x;

    for (int e = tid; e < 729; e += 256)
        As[e] = Ab[(size_t)e * 1024 + c];

    const int lane = tid & 63;
    const int w = tid >> 6;
    const int lr = lane & 15;
    const int lk = (lane >> 4) * 8;
    const bf16* Vc = Vt + (size_t)c * 64 * 224;

    bf16x8 bfr[7];
    #pragma unroll
    for (int ks = 0; ks < 7; ++ks)
        bfr[ks] = *(const bf16x8*)&Vc[(size_t)(w * 16 + lr) * 224 + ks * 32 + lk];

    __syncthreads();   // As ready

    const bf16 z = __float2bfloat16(0.0f);
    const int crow = (lane >> 4) * 4;
    const int bb = w * 16 + (lane & 15);

    #pragma unroll
    for (int mh = 0; mh < 2; ++mh) {
        const int mbase = mh * 112;
        if (tid < 224) {
            const int i = tid / 14, j = tid - i * 14;
            const bool kvalid = tid < 196;
            int p = mbase / 14, q = 0;
            for (int r = 0; r < 112; ++r) {
                bf16 val = z;
                if (kvalid && (mbase + r) < 196)
                    val = As[(p - i + 13) * 27 + (q - j + 13)];
                Ts[r * 232 + tid] = val;
                if (++q == 14) { q = 0; ++p; }
            }
        }
        __syncthreads();   // Ts ready

        f32x4 acc[7] = {};
        #pragma unroll
        for (int ks = 0; ks < 7; ++ks)
            #pragma unroll
            for (int mi = 0; mi < 7; ++mi) {
                bf16x8 a = *(const bf16x8*)&Ts[(mi * 16 + lr) * 232 + ks * 32 + lk];
                acc[mi] = __builtin_amdgcn_mfma_f32_16x16x32_bf16(a, bfr[ks], acc[mi], 0, 0, 0);
            }

        #pragma unroll
        for (int mi = 0; mi < 7; ++mi) {
            int pq = mbase + mi * 16 + crow;
            #pragma unroll
            for (int r = 0; r < 4; ++r)
                if (pq + r < 196)
                    Yt[((size_t)c * 196 + pq + r) * 64 + bb] = __float2bfloat16(acc[mi][r]);
        }
        __syncthreads();   // Ts reads done before next build
    }
}

// ---------------------------------------------------------------------------
__global__ __launch_bounds__(256) void k_gate(bf16* __restrict__ uv,
                                              const bf16* __restrict__ Yt) {
    const int pq = blockIdx.x;
    const int ct = blockIdx.y;
    const int cb = (int)blockIdx.z * 512;
    const int tid = threadIdx.x;
    __shared__ float t[64][65];
    for (int f = tid; f < 64 * 64; f += 256) {
        int cr = f >> 6, bcol = f & 63;
        t[cr][bcol] = __bfloat162float(Yt[((size_t)(cb + ct * 64 + cr) * 196 + pq) * 64 + bcol]);
    }
    __syncthreads();
    for (int f = tid; f < 64 * 64; f += 256) {
        int br = f >> 6, cc = f & 63;
        size_t row = (size_t)br * 196 + pq;
        int cglob = cb + ct * 64 + cc;
        float uu = __bfloat162float(uv[row * 2048 + cglob]);
        uv[row * 2048 + 1024 + cglob] = __float2bfloat16(t[cc][br] * uu);
    }
}

// ---------------------------------------------------------------------------
extern "C" void kernel_launch(void* const* d_in, const int* in_sizes, int n_in,
                              void* d_out, int out_size, void* d_ws, size_t ws_size,
                              hipStream_t stream) {
    const float* x    = (const float*)d_in[0];
    const float* Wu   = (const float*)d_in[3];
    const float* bu   = (const float*)d_in[4];
    const float* Wv   = (const float*)d_in[5];
    const float* bv   = (const float*)d_in[6];
    const float* Wo   = (const float*)d_in[7];
    const float* bo   = (const float*)d_in[8];
    const float* rpw  = (const float*)d_in[9];
    const float* rpb  = (const float*)d_in[10];
    const float* w1   = (const float*)d_in[11];
    const float* b1   = (const float*)d_in[12];
    const float* w2   = (const float*)d_in[13];
    const float* b2   = (const float*)d_in[14];
    const float* w3   = (const float*)d_in[15];
    const float* b3   = (const float*)d_in[16];
    const float* wOut = (const float*)d_in[17];
    const float* bOut = (const float*)d_in[18];

    char* ws = (char*)d_ws;
    size_t off = 0;
    auto take = [&](size_t bytes) { char* p = ws + off; off += (bytes + 255) & ~size_t(255); return p; };
    bf16*  rnA    = (bf16*)take((size_t)768 * 512 * 2);
    bf16*  rnB    = (bf16*)take((size_t)768 * 512 * 2);
    float* p1     = (float*)take((size_t)768 * 8 * 4);
    float* p2     = (float*)take((size_t)768 * 8 * 4);
    float* p3     = (float*)take((size_t)768 * 8 * 4);
    bf16*  Ab     = (bf16*)take((size_t)RPOS * 1024 * 2);
    bf16*  xb     = (bf16*)take((size_t)ROWS * EE * 2);
    bf16*  WuvT   = (bf16*)take((size_t)2048 * 512 * 2);
    bf16*  WoT    = (bf16*)take((size_t)512 * 1024 * 2);
    bf16*  w1T    = (bf16*)take((size_t)512 * 512 * 2);
    bf16*  w2T    = (bf16*)take((size_t)512 * 512 * 2);
    bf16*  w3T    = (bf16*)take((size_t)512 * 512 * 2);
    bf16*  wOutT  = (bf16*)take((size_t)1024 * 512 * 2);
    float* biasUv = (float*)take(2048 * 4);
    bf16*  uvb    = (bf16*)take((size_t)ROWS * 2048 * 2);
    bf16*  Vt     = (bf16*)take((size_t)1024 * 64 * 224 * 2);
    bf16*  Yt     = (bf16*)take((size_t)1024 * 196 * 64 * 2);

    // --- all prep (incl. RPE pos+norm) ---
    k_prep<<<9825, 256, 0, stream>>>(Wu, Wv, Wo, w1, w2, w3, wOut, bu, bv, x,
                                     rpw, rpb,
                                     WuvT, WoT, w1T, w2T, w3T, wOutT, biasUv, xb, rnA);

    // --- uv GEMM + RPE L1 co-dispatched (440 blocks) ---
    k_uv_l1<<<UVNWG + 48, 512, 0, stream>>>(xb, 512, WuvT, biasUv, uvb, 2048, 8,
                                            rnA, w1T, b1, p1, rnB);

    // --- v transpose (b 0..31) + RPE L2; then (b 32..63) + RPE L3 ---
    k_vt_rpe<<<608, 256, 0, stream>>>(uvb, Vt, 0,  rnB, w2T, b2, p1, p2, rnA);
    k_vt_rpe<<<608, 256, 0, stream>>>(uvb, Vt, 32, rnA, w3T, b3, p2, p3, rnB);

    // --- RPE L4 (Toeplitz coeffs) ---
    k_rpe_gemm<1, 2><<<dim3(16, 12), 256, 0, stream>>>(rnB, wOutT, bOut, p3, nullptr, Ab, RPOS, 1024, 512);

    // --- Toeplitz conv (MFMA), both mh halves per block ---
    k_convm<<<dim3(512, 2), 256, 0, stream>>>(Ab, Vt, Yt);

    // --- gating ---
    k_gate<<<dim3(196, 8, 2), 256, 0, stream>>>(uvb, Yt);

    // --- out = g @ Wo + bo  (m97 128^2, grid 392) ---
    k_mgemm<0, float><<<dim3(4, 98), 256, 0, stream>>>(uvb + 1024, 2048, WoT, bo,
                                                       (float*)d_out, 512, ROWS, 512, 1024);
}